// Round 13
// baseline (319.389 us; speedup 1.0000x reference)
//
#include <hip/hip_runtime.h>
#include <math.h>

constexpr int B  = 32;
constexpr int T0 = 2048;
constexpr int D  = 512;

// ws layout (in floats)
constexpr size_t OFF_PART = 0;                              // B*64*8 per-block TDA partials
constexpr size_t OFF_ATTN = OFF_PART + (size_t)B * 64 * 8;  // B*D
constexpr size_t OFF_INJ  = OFF_ATTN + (size_t)B * D;       // 3*B*D

typedef float nfloat4 __attribute__((ext_vector_type(4)));  // native vec for nt builtins

template<int LO>
__device__ __forceinline__ void wredt_add(float& v) {
  #pragma unroll
  for (int off = 32; off >= LO; off >>= 1) v += __shfl_down(v, off);
}
template<int LO>
__device__ __forceinline__ void wredt_min(float& v) {
  #pragma unroll
  for (int off = 32; off >= LO; off >>= 1) v = fminf(v, __shfl_down(v, off));
}
template<int LO>
__device__ __forceinline__ void wredt_max(float& v) {
  #pragma unroll
  for (int off = 32; off >= LO; off >>= 1) v = fmaxf(v, __shfl_down(v, off));
}
__device__ __forceinline__ void wred_add(float& v) { wredt_add<4>(v); }

__device__ __forceinline__ void nt_store4(float* p, float4 v) {
  nfloat4 nv;
  nv.x = v.x; nv.y = v.y; nv.z = v.z; nv.w = v.w;
  __builtin_nontemporal_store(nv, (nfloat4*)p);
}
__device__ __forceinline__ float4 nt_load4(const float* p) {
  nfloat4 nv = __builtin_nontemporal_load((const nfloat4*)p);
  return make_float4(nv.x, nv.y, nv.z, nv.w);
}

// complex helpers on float4 = two interleaved complex numbers
__device__ __forceinline__ float4 cadd(float4 a, float4 b) {
  return make_float4(a.x+b.x, a.y+b.y, a.z+b.z, a.w+b.w);
}
__device__ __forceinline__ float4 csub(float4 a, float4 b) {
  return make_float4(a.x-b.x, a.y-b.y, a.z-b.z, a.w-b.w);
}
__device__ __forceinline__ float4 cmul(float4 v, float2 w) {    // v * w
  return make_float4(v.x*w.x - v.y*w.y, v.x*w.y + v.y*w.x,
                     v.z*w.x - v.w*w.y, v.z*w.y + v.w*w.x);
}
__device__ __forceinline__ float4 cmulc(float4 v, float2 w) {   // v * conj(w)
  return make_float4(v.x*w.x + v.y*w.y, v.y*w.x - v.x*w.y,
                     v.z*w.x + v.w*w.y, v.w*w.x - v.z*w.y);
}
__device__ __forceinline__ float4 cmul_mi(float4 v) {           // v * (-i)
  return make_float4(v.y, -v.x, v.w, -v.z);
}
__device__ __forceinline__ float4 cmul_pi(float4 v) {           // v * (+i)
  return make_float4(-v.y, v.x, -v.w, v.z);
}

#define R8C 0.70710678118654752f

// radix-8 DIF: x[m] at stride-Q positions; tA/tB/tC = stage twiddles.
__device__ __forceinline__ void r8_fwd(float4 x[8], float2 tA, float2 tB, float2 tC) {
  float4 a0 = cadd(x[0], x[4]), a1 = cadd(x[1], x[5]);
  float4 a2 = cadd(x[2], x[6]), a3 = cadd(x[3], x[7]);
  float4 b0 = cmul(csub(x[0], x[4]), tA);
  float4 b1 = cmul(cmul(csub(x[1], x[5]), tA), make_float2(R8C, -R8C));
  float4 b2 = cmul_mi(cmul(csub(x[2], x[6]), tA));
  float4 b3 = cmul(cmul(csub(x[3], x[7]), tA), make_float2(-R8C, -R8C));
  float4 p0 = cadd(a0, a2), p1 = cmul(csub(a0, a2), tB);
  float4 p2 = cadd(a1, a3), p3 = cmul_mi(cmul(csub(a1, a3), tB));
  x[0] = cadd(p0, p2); x[1] = cmul(csub(p0, p2), tC);
  x[2] = cadd(p1, p3); x[3] = cmul(csub(p1, p3), tC);
  float4 q0 = cadd(b0, b2), q1 = cmul(csub(b0, b2), tB);
  float4 q2 = cadd(b1, b3), q3 = cmul_mi(cmul(csub(b1, b3), tB));
  x[4] = cadd(q0, q2); x[5] = cmul(csub(q0, q2), tC);
  x[6] = cadd(q1, q3); x[7] = cmul(csub(q1, q3), tC);
}

// radix-8 DIT inverse (sign +1): x[m] at stride-h; wA/wB/wC conj-applied.
__device__ __forceinline__ void r8_inv(float4 x[8], float2 wA, float2 wB, float2 wC) {
  float4 t1 = cmulc(x[1], wA); float4 u0 = cadd(x[0], t1), u1 = csub(x[0], t1);
  float4 t3 = cmulc(x[3], wA); float4 u2 = cadd(x[2], t3), u3 = csub(x[2], t3);
  float4 t5 = cmulc(x[5], wA); float4 u4 = cadd(x[4], t5), u5 = csub(x[4], t5);
  float4 t7 = cmulc(x[7], wA); float4 u6 = cadd(x[6], t7), u7 = csub(x[6], t7);
  float4 s2 = cmulc(u2, wB), s3 = cmul_pi(cmulc(u3, wB));
  float4 y0 = cadd(u0, s2), y1 = cadd(u1, s3), y2 = csub(u0, s2), y3 = csub(u1, s3);
  float4 s6 = cmulc(u6, wB), s7 = cmul_pi(cmulc(u7, wB));
  float4 y4 = cadd(u4, s6), y5 = cadd(u5, s7), y6 = csub(u4, s6), y7 = csub(u5, s7);
  float4 c0 = cmulc(y4, wC);
  float4 c1 = cmul(cmulc(y5, wC), make_float2(R8C, R8C));
  float4 c2 = cmul_pi(cmulc(y6, wC));
  float4 c3 = cmul(cmulc(y7, wC), make_float2(-R8C, R8C));
  x[0] = cadd(y0, c0); x[1] = cadd(y1, c1); x[2] = cadd(y2, c2); x[3] = cadd(y3, c3);
  x[4] = csub(y0, c0); x[5] = csub(y1, c1); x[6] = csub(y2, c2); x[7] = csub(y3, c3);
}

// ---- fused TDA: stats + spectral centroid. Block = (b, 8 consecutive d's) ----
__global__ __launch_bounds__(512) void k_tda(const float* __restrict__ x,
                                              float* __restrict__ part) {
  __shared__ float4 buf[T0 * 2];           // [t][2 quads]; quad f = cols 4f..4f+3
  __shared__ float2 tw[1024];              // e^{-i pi k/1024}; overlaid by scratch first
  __shared__ float perd[8][8];             // per-d features (this block's 8 d's)
  float* scr = (float*)tw;                 // wave-partial scratch
  const int tid  = threadIdx.x;
  // pairing swizzle: partner blocks (same 64B line) differ by 8 in flat ID
  const int L = blockIdx.x + 64 * blockIdx.y;   // grid (64, 32)
  const int m = (L >> 3) & 1;
  const int q = (L & 7) | ((L >> 4) << 3);      // 0..1023
  const int eb = (q & 31) * 2 + m;              // 0..63 (8 d's each)
  const int b  = q >> 5;                        // 0..31
  const int f    = tid & 1;                // quad 0..1
  const int rIdx = tid >> 1;               // 0..255
  const int lane = tid & 63;
  const int wv   = tid >> 6;               // 0..7
  const float* base = x + (size_t)b * T0 * D + eb * 8 + f * 4;

  // ---- load + in-register stats ----
  float4 s1 = {0,0,0,0}, s2 = {0,0,0,0}, st = {0,0,0,0};
  float4 mn = {INFINITY,INFINITY,INFINITY,INFINITY};
  float4 mx = {-INFINITY,-INFINITY,-INFINITY,-INFINITY};
  #pragma unroll
  for (int u = 0; u < 8; ++u) {
    int t = rIdx + 256 * u;
    float4 v = *(const float4*)&base[(size_t)t * D];
    buf[t * 2 + f] = v;
    float tf = (float)t;
    s1.x += v.x; s1.y += v.y; s1.z += v.z; s1.w += v.w;
    s2.x = fmaf(v.x,v.x,s2.x); s2.y = fmaf(v.y,v.y,s2.y);
    s2.z = fmaf(v.z,v.z,s2.z); s2.w = fmaf(v.w,v.w,s2.w);
    st.x = fmaf(tf,v.x,st.x); st.y = fmaf(tf,v.y,st.y);
    st.z = fmaf(tf,v.z,st.z); st.w = fmaf(tf,v.w,st.w);
    mn.x = fminf(mn.x,v.x); mn.y = fminf(mn.y,v.y); mn.z = fminf(mn.z,v.z); mn.w = fminf(mn.w,v.w);
    mx.x = fmaxf(mx.x,v.x); mx.y = fmaxf(mx.y,v.y); mx.z = fmaxf(mx.z,v.z); mx.w = fmaxf(mx.w,v.w);
  }
  __syncthreads();
  // lag-1 cross terms from LDS
  float4 cc = {0,0,0,0};
  #pragma unroll
  for (int u = 0; u < 8; ++u) {
    int t = rIdx + 256 * u;
    if (t < T0 - 1) {
      float4 a = buf[t * 2 + f];
      float4 nb = buf[(t + 1) * 2 + f];
      cc.x = fmaf(a.x,nb.x,cc.x); cc.y = fmaf(a.y,nb.y,cc.y);
      cc.z = fmaf(a.z,nb.z,cc.z); cc.w = fmaf(a.w,nb.w,cc.w);
    }
  }
  wredt_add<2>(s1.x); wredt_add<2>(s1.y); wredt_add<2>(s1.z); wredt_add<2>(s1.w);
  wredt_add<2>(s2.x); wredt_add<2>(s2.y); wredt_add<2>(s2.z); wredt_add<2>(s2.w);
  wredt_add<2>(st.x); wredt_add<2>(st.y); wredt_add<2>(st.z); wredt_add<2>(st.w);
  wredt_add<2>(cc.x); wredt_add<2>(cc.y); wredt_add<2>(cc.z); wredt_add<2>(cc.w);
  wredt_min<2>(mn.x); wredt_min<2>(mn.y); wredt_min<2>(mn.z); wredt_min<2>(mn.w);
  wredt_max<2>(mx.x); wredt_max<2>(mx.y); wredt_max<2>(mx.z); wredt_max<2>(mx.w);
  if (lane < 2) {                           // lane == f here
    float* p = scr + ((size_t)wv * 2 + f) * 24;
    p[0]=s1.x; p[1]=s2.x; p[2]=st.x; p[3]=cc.x; p[4]=mn.x; p[5]=mx.x;
    p[6]=s1.y; p[7]=s2.y; p[8]=st.y; p[9]=cc.y; p[10]=mn.y; p[11]=mx.y;
    p[12]=s1.z; p[13]=s2.z; p[14]=st.z; p[15]=cc.z; p[16]=mn.z; p[17]=mx.z;
    p[18]=s1.w; p[19]=s2.w; p[20]=st.w; p[21]=cc.w; p[22]=mn.w; p[23]=mx.w;
  }
  __syncthreads();
  if (tid < 8) {
    const int dl = tid;                     // 0..7 local d
    const int fq = dl >> 2, c = dl & 3;
    float S1=0.f, S2=0.f, St=0.f, C=0.f, MN=INFINITY, MX=-INFINITY;
    for (int w = 0; w < 8; ++w) {
      const float* p = scr + ((size_t)w * 2 + fq) * 24 + c * 6;
      S1 += p[0]; S2 += p[1]; St += p[2]; C += p[3];
      MN = fminf(MN, p[4]); MX = fmaxf(MX, p[5]);
    }
    const float x0 = ((const float*)buf)[dl];
    const float xl = ((const float*)buf)[(size_t)(T0 - 1) * 8 + dl];
    const float Tf = (float)T0;
    const float mean = S1 / Tf;
    const float sxx  = S2 - S1 * S1 / Tf;
    const float stdv = sqrtf(fmaxf(sxx / (Tf - 1.f), 0.f));
    const float tbar = (Tf - 1.f) * 0.5f;
    const float Sic  = Tf * (Tf * Tf - 1.f) / 12.f;
    float trend = (St - tbar * S1) / sqrtf(sxx * Sic);
    if (isnan(trend)) trend = 0.f;
    const float na = Tf - 1.f;
    const float Sa = S1 - xl, Sb = S1 - x0;
    const float an  = C - Sa * Sb / na;
    const float sa2 = (S2 - xl * xl) - Sa * Sa / na;
    const float sb2 = (S2 - x0 * x0) - Sb * Sb / na;
    float ac = an / sqrtf(sa2 * sb2);
    if (isnan(ac)) ac = 0.f;
    perd[dl][0] = mean; perd[dl][1] = stdv; perd[dl][2] = MN;
    perd[dl][3] = MX;   perd[dl][4] = trend; perd[dl][5] = ac;
  }
  __syncthreads();   // scr reads done -> tw may be overwritten

  // ---- twiddles ----
  for (int k = tid; k < 1024; k += 512) {
    float sw, cw;
    sincosf(-(float)M_PI * (float)k * (1.0f / 1024.0f), &sw, &cw);
    tw[k] = make_float2(cw, sw);
  }
  __syncthreads();

  // ---- in-place DIF FFT, 2048-pt: 3 radix-8 passes + 1 radix-4 (unit) ----
  for (int stg = 0; stg < 9; stg += 3) {
    const int qsh = 8 - stg;            // log2(Q)
    const int Q = 1 << qsh;
    int pp = tid & 1;
    int gi = tid >> 1;                  // 0..255
    int j3 = gi & (Q - 1);
    int g  = gi >> qsh;
    int bs = (g << (qsh + 3)) + j3;
    float2 tA = tw[j3 << stg];
    float2 tB = tw[j3 << (stg + 1)];
    float2 tC = tw[j3 << (stg + 2)];
    float4 xx[8];
    #pragma unroll
    for (int mm = 0; mm < 8; ++mm) xx[mm] = buf[(bs + mm * Q) * 2 + pp];
    r8_fwd(xx, tA, tB, tC);
    #pragma unroll
    for (int mm = 0; mm < 8; ++mm) buf[(bs + mm * Q) * 2 + pp] = xx[mm];
    __syncthreads();
  }
  // tail radix-4 (stages 9,10; unit twiddles)
  #pragma unroll
  for (int it = 0; it < 2; ++it) {
    int sl = it * 512 + tid;
    int pp = sl & 1;
    int qi = sl >> 1;                   // 0..511
    int bs = qi << 2;
    float4 x0 = buf[bs*2+pp], x1 = buf[(bs+1)*2+pp];
    float4 x2 = buf[(bs+2)*2+pp], x3 = buf[(bs+3)*2+pp];
    float4 u0 = cadd(x0, x2);
    float4 t2 = csub(x0, x2);
    float4 u1 = cadd(x1, x3);
    float4 t3 = cmul_mi(csub(x1, x3));
    buf[bs*2+pp]     = cadd(u0, u1);
    buf[(bs+1)*2+pp] = csub(u0, u1);
    buf[(bs+2)*2+pp] = cadd(t2, t3);
    buf[(bs+3)*2+pp] = csub(t2, t3);
  }
  __syncthreads();
  // buf[p] = Z[rev11(p)]

  // ---- centroid: unpack real spectra per column, k = 0..1023 ----
  float4 num = {0,0,0,0}, den = {0,0,0,0};
  #pragma unroll
  for (int it = 0; it < 4; ++it) {
    int sl = it * 512 + tid;
    int pp = sl & 1;
    int k = sl >> 1;
    int p1 = __brev((unsigned)k) >> 21;
    int p2 = __brev((unsigned)((T0 - k) & (T0 - 1))) >> 21;
    float4 zk = buf[p1 * 2 + pp];
    float4 zm = buf[p2 * 2 + pp];
    float kf = (float)k;
    float arx = 0.5f*(zk.x+zm.x), ary = 0.5f*(zk.y-zm.y);
    float brx = 0.5f*(zk.y+zm.y), bry = 0.5f*(zm.x-zk.x);
    float pa = arx*arx + ary*ary, pb = brx*brx + bry*bry;
    num.x = fmaf(kf, pa, num.x); den.x += pa;
    num.y = fmaf(kf, pb, num.y); den.y += pb;
    arx = 0.5f*(zk.z+zm.z); ary = 0.5f*(zk.w-zm.w);
    brx = 0.5f*(zk.w+zm.w); bry = 0.5f*(zm.z-zk.z);
    pa = arx*arx + ary*ary; pb = brx*brx + bry*bry;
    num.z = fmaf(kf, pa, num.z); den.z += pa;
    num.w = fmaf(kf, pb, num.w); den.w += pb;
  }
  wredt_add<2>(num.x); wredt_add<2>(num.y); wredt_add<2>(num.z); wredt_add<2>(num.w);
  wredt_add<2>(den.x); wredt_add<2>(den.y); wredt_add<2>(den.z); wredt_add<2>(den.w);
  if (lane < 2) {
    float* p = scr + ((size_t)wv * 2 + f) * 8;
    p[0]=num.x; p[1]=num.y; p[2]=num.z; p[3]=num.w;
    p[4]=den.x; p[5]=den.y; p[6]=den.z; p[7]=den.w;
  }
  __syncthreads();
  if (tid < 8) {
    const int dl = tid;
    const int fq = dl >> 2, c = dl & 3;
    float N = 0.f, Dn = 0.f;
    for (int w = 0; w < 8; ++w) {
      const float* p = scr + ((size_t)w * 2 + fq) * 8;
      N += p[c]; Dn += p[4 + c];
    }
    float cent = N / Dn;
    if (isnan(cent)) cent = 0.f;
    perd[dl][6] = cent;
  }
  __syncthreads();
  if (tid < 7) {
    float s = 0.f;
    #pragma unroll
    for (int dl = 0; dl < 8; ++dl) s += perd[dl][tid];
    part[((size_t)b * 64 + eb) * 8 + tid] = s;
  }
}

// --------------- attn = sigmoid(relu(tda@w1+b1)@w2+b2); inj_l -----------------
__global__ __launch_bounds__(512) void k_weights(const float* __restrict__ part,
    const float* __restrict__ w1, const float* __restrict__ b1,
    const float* __restrict__ w2, const float* __restrict__ b2,
    const float* __restrict__ wi0, const float* __restrict__ bi0,
    const float* __restrict__ wi1, const float* __restrict__ bi1,
    const float* __restrict__ wi2, const float* __restrict__ bi2,
    float* __restrict__ attn, float* __restrict__ inj) {
  const int b = blockIdx.x;
  const int j = threadIdx.x;
  __shared__ float td[7];
  __shared__ float h[512];
  if (j < 7) {
    float s = 0.f;
    for (int w = 0; w < 64; ++w) s += part[((size_t)b * 64 + w) * 8 + j];
    td[j] = s * (1.0f / (float)D);
  }
  __syncthreads();
  float a = b1[j];
  #pragma unroll
  for (int f = 0; f < 7; ++f) a = fmaf(td[f], w1[f * D + j], a);
  h[j] = fmaxf(a, 0.0f);
  __syncthreads();
  float a2 = b2[j];
  for (int k = 0; k < D; ++k) a2 = fmaf(h[k], w2[k * D + j], a2);
  attn[(size_t)b * D + j] = 1.0f / (1.0f + expf(-a2));
  const float* wis[3] = {wi0, wi1, wi2};
  const float* bis[3] = {bi0, bi1, bi2};
  #pragma unroll
  for (int l = 0; l < 3; ++l) {
    float ai = bis[l][j];
    #pragma unroll
    for (int f = 0; f < 7; ++f) ai = fmaf(td[f], wis[l][f * D + j], ai);
    inj[(size_t)l * B * D + (size_t)b * D + j] = 0.3f * ai;
  }
}

// --------- FFT 2x spectral interp, batched 8 pairs/block, in-place ------------
// high is the LAST read of that level -> non-temporal load (preserve L3 for
// the low levels that get re-read). low nt-loaded only when COPY (level3,
// single reader). Outputs nt-stored.
template<int S, int NT, bool COPY>
__global__ __launch_bounds__(NT) void k_interp(const float* __restrict__ low,
                                                const float* __restrict__ high,
                                                const float* __restrict__ attn,
                                                const float* __restrict__ inj,
                                                float* __restrict__ out,
                                                float* __restrict__ copy_out) {
  constexpr int LOG2S = (S == 1024) ? 10 : (S == 512) ? 9 : 8;
  constexpr int WAVES = NT / 64;
  constexpr int RPT   = S / (NT / 4);          // rows per thread
  constexpr int R8IT  = S / 2;                 // items per radix-8 pass
  __shared__ float4 buf[S * 4];
  __shared__ float2 tw[S];
  __shared__ float4 scrA[WAVES][4];
  __shared__ float4 Zh4[4];
  const int tid  = threadIdx.x;
  // pairing swizzle: partner blocks (eb pair sharing 128B lines) differ by 8
  const int L = blockIdx.x + 32 * blockIdx.y;  // grid (32, 32) flat 0..1023
  const int m = (L >> 3) & 1;
  const int q = (L & 7) | ((L >> 4) << 3);     // 0..511
  const int eb = (q & 15) * 2 + m;             // 0..31
  const int b  = q >> 4;                       // 0..31
  const int f    = tid & 3;
  const int rIdx = tid >> 2;
  const int lane = tid & 63;
  const int wv   = tid >> 6;
  const int d0   = eb * 16;

  const float* lowb  = low  + (size_t)b * S * D + d0 + 4 * f;
  const float* highb = high + (size_t)b * (2 * S) * D + d0 + 4 * f;
  float*       outb  = out  + (size_t)b * (2 * S) * D + d0 + 4 * f;
  float*       cpb   = COPY ? copy_out + (size_t)b * S * D + d0 + 4 * f : nullptr;

  // ---- load (full-line rows) + z kept in regs + alternating-sum partials ----
  float4 zreg[RPT];
  float4 acc = {0,0,0,0};
  #pragma unroll
  for (int u = 0; u < RPT; ++u) {
    int t = rIdx + (NT / 4) * u;
    float4 v = COPY ? nt_load4(&lowb[(size_t)t * D])
                    : *(const float4*)&lowb[(size_t)t * D];
    zreg[u] = v;
    buf[t * 4 + f] = v;
    if (COPY) nt_store4(&cpb[(size_t)t * D], v);
    acc.x += v.x; acc.y += v.y; acc.z += v.z; acc.w += v.w;
  }
  if (rIdx & 1) { acc.x = -acc.x; acc.y = -acc.y; acc.z = -acc.z; acc.w = -acc.w; }
  for (int k = tid; k < S; k += NT) {
    float sw, cw;
    sincosf(-(float)M_PI * (float)k * (1.0f / (float)S), &sw, &cw);
    tw[k] = make_float2(cw, sw);
  }
  wred_add(acc.x); wred_add(acc.y); wred_add(acc.z); wred_add(acc.w);
  if (lane < 4) scrA[wv][f] = acc;             // f == lane
  __syncthreads();
  if (tid < 4) {
    float4 s = scrA[0][tid];
    for (int w = 1; w < WAVES; ++w) {
      float4 qv = scrA[w][tid];
      s.x += qv.x; s.y += qv.y; s.z += qv.z; s.w += qv.w;
    }
    Zh4[tid] = s;
  }
  __syncthreads();

  const float inv4S = 1.0f / (4.0f * (float)S);
  const float4 at4 = *(const float4*)&attn[(size_t)b * D + d0 + 4 * f];
  const float4 in4 = *(const float4*)&inj [(size_t)b * D + d0 + 4 * f];
  float4 Zs = Zh4[f];
  Zs.x *= inv4S; Zs.y *= inv4S; Zs.z *= inv4S; Zs.w *= inv4S;

  // ---- forward DIF (natural -> bitrev), radix-8 passes ----
  for (int stg = 0; stg + 2 < LOG2S; stg += 3) {
    const int qsh = LOG2S - 3 - stg;
    const int Q = 1 << qsh;
    #pragma unroll
    for (int it = 0; it < (R8IT + NT - 1) / NT; ++it) {
      int sl = it * NT + tid;
      if (sl < R8IT) {
        int pp = sl & 3;
        int gi = sl >> 2;
        int j3 = gi & (Q - 1);
        int g  = gi >> qsh;
        int bs = (g << (qsh + 3)) + j3;
        float2 tA = tw[j3 << (stg + 1)];
        float2 tB = tw[j3 << (stg + 2)];
        float2 tC = tw[j3 << (stg + 3)];
        float4 xx[8];
        #pragma unroll
        for (int mm = 0; mm < 8; ++mm) xx[mm] = buf[(bs + mm * Q) * 4 + pp];
        r8_fwd(xx, tA, tB, tC);
        #pragma unroll
        for (int mm = 0; mm < 8; ++mm) buf[(bs + mm * Q) * 4 + pp] = xx[mm];
      }
      __syncthreads();
    }
  }
  if (LOG2S % 3 == 1) {                  // tail radix-2 (unit twiddles)
    #pragma unroll
    for (int it = 0; it < (2 * S) / NT; ++it) {
      int sl = it * NT + tid;
      int pp = sl & 3;
      int bi = sl >> 2;
      int i = bi * 2;
      float4 a = buf[i * 4 + pp];
      float4 c4 = buf[(i + 1) * 4 + pp];
      buf[i * 4 + pp]       = cadd(a, c4);
      buf[(i + 1) * 4 + pp] = csub(a, c4);
    }
    __syncthreads();
  }
  if (LOG2S % 3 == 2) {                  // tail radix-4 (unit twiddles)
    #pragma unroll
    for (int it = 0; it < S / NT; ++it) {
      int sl = it * NT + tid;
      int pp = sl & 3;
      int qi = sl >> 2;
      int bs = qi << 2;
      float4 x0 = buf[bs*4+pp], x1 = buf[(bs+1)*4+pp];
      float4 x2 = buf[(bs+2)*4+pp], x3 = buf[(bs+3)*4+pp];
      float4 u0 = cadd(x0, x2);
      float4 t2 = csub(x0, x2);
      float4 u1 = cadd(x1, x3);
      float4 t3 = cmul_mi(csub(x1, x3));
      buf[bs*4+pp]     = cadd(u0, u1);
      buf[(bs+1)*4+pp] = csub(u0, u1);
      buf[(bs+2)*4+pp] = cadd(t2, t3);
      buf[(bs+3)*4+pp] = csub(t2, t3);
    }
    __syncthreads();
  }
  // buf[p] = Z[rev(p)]

  // ---- inverse DIT (bitrev -> natural), radix-8 passes; g fused in pass 0 ----
  for (int stg = 0; stg + 2 < LOG2S; stg += 3) {
    const int h = 1 << stg;
    #pragma unroll
    for (int it = 0; it < (R8IT + NT - 1) / NT; ++it) {
      int sl = it * NT + tid;
      if (sl < R8IT) {
        int pp = sl & 3;
        int gi = sl >> 2;
        int j  = gi & (h - 1);
        int G  = gi >> stg;
        int bs = (G << (stg + 3)) + j;
        float2 wA = tw[j << (LOG2S - stg)];
        float2 wB = tw[j << (LOG2S - stg - 1)];
        float2 wC = tw[j << (LOG2S - stg - 2)];
        float4 xx[8];
        if (stg == 0) {
          #pragma unroll
          for (int mm = 0; mm < 8; ++mm) {
            int p = bs + mm;
            int k = __brev((unsigned)p) >> (32 - LOG2S);
            float2 w = tw[k];
            float sgn = (k < S / 2) ? 1.f : (k == S / 2) ? 0.f : -1.f;
            float4 v = cmulc(buf[p * 4 + pp], w);
            v.x *= sgn; v.y *= sgn; v.z *= sgn; v.w *= sgn;
            xx[mm] = v;
          }
        } else {
          #pragma unroll
          for (int mm = 0; mm < 8; ++mm) xx[mm] = buf[(bs + mm * h) * 4 + pp];
        }
        r8_inv(xx, wA, wB, wC);
        #pragma unroll
        for (int mm = 0; mm < 8; ++mm) buf[(bs + mm * h) * 4 + pp] = xx[mm];
      }
      __syncthreads();
    }
  }
  if (LOG2S % 3 == 1) {                  // tail radix-2 at stg = LOG2S-1
    const int stg = LOG2S - 1;
    const int h = 1 << stg;
    #pragma unroll
    for (int it = 0; it < (2 * S) / NT; ++it) {
      int sl = it * NT + tid;
      int pp = sl & 3;
      int bi = sl >> 2;
      int j = bi & (h - 1);
      int g = bi >> stg;
      int i = (g << (stg + 1)) + j;
      float2 w = tw[j << (LOG2S - stg)];
      float4 a = buf[i * 4 + pp];
      float4 v = buf[(i + h) * 4 + pp];
      float4 t = cmulc(v, w);
      buf[i * 4 + pp]       = cadd(a, t);
      buf[(i + h) * 4 + pp] = csub(a, t);
    }
    __syncthreads();
  }
  if (LOG2S % 3 == 2) {                  // tail radix-4 at stg = LOG2S-2
    const int stg = LOG2S - 2;
    const int h = 1 << stg;
    #pragma unroll
    for (int it = 0; it < S / NT; ++it) {
      int sl = it * NT + tid;
      int pp = sl & 3;
      int qi = sl >> 2;
      int j = qi & (h - 1);
      int g = qi >> stg;
      int bs = (g << (stg + 2)) + j;
      float2 wA = tw[j << (LOG2S - stg)];
      float2 wB = tw[j << (LOG2S - stg - 1)];
      float4 x0 = buf[bs * 4 + pp];
      float4 x1 = buf[(bs + h) * 4 + pp];
      float4 x2 = buf[(bs + 2 * h) * 4 + pp];
      float4 x3 = buf[(bs + 3 * h) * 4 + pp];
      float4 t1 = cmulc(x1, wA);
      float4 u0 = cadd(x0, t1), u1 = csub(x0, t1);
      float4 t3 = cmulc(x3, wA);
      float4 u2 = cadd(x2, t3), u3 = csub(x2, t3);
      float4 s2c = cmulc(u2, wB);
      float4 s3c = cmul_pi(cmulc(u3, wB));
      buf[bs * 4 + pp]           = cadd(u0, s2c);
      buf[(bs + h) * 4 + pp]     = cadd(u1, s3c);
      buf[(bs + 2 * h) * 4 + pp] = csub(u0, s2c);
      buf[(bs + 3 * h) * 4 + pp] = csub(u1, s3c);
    }
    __syncthreads();
  }

  // ---- even + odd outputs together; high nt-loaded, outputs nt-stored ----
  #pragma unroll
  for (int u = 0; u < RPT; ++u) {
    int j = rIdx + (NT / 4) * u;
    float4 z = zreg[u];
    float sg = (j & 1) ? -1.f : 1.f;
    float4 res_e;
    res_e.x = fmaf(0.25f, z.x, sg * Zs.x);
    res_e.y = fmaf(0.25f, z.y, sg * Zs.y);
    res_e.z = fmaf(0.25f, z.z, sg * Zs.z);
    res_e.w = fmaf(0.25f, z.w, sg * Zs.w);
    float4 y = buf[j * 4 + f];
    float4 h0 = nt_load4(&highb[(size_t)(2 * j) * D]);
    float4 h1 = nt_load4(&highb[(size_t)(2 * j + 1) * D]);
    float4 o0, o1;
    o0.x = fmaf(h0.x - res_e.x, at4.x, in4.x);
    o0.y = fmaf(h0.y - res_e.y, at4.y, in4.y);
    o0.z = fmaf(h0.z - res_e.z, at4.z, in4.z);
    o0.w = fmaf(h0.w - res_e.w, at4.w, in4.w);
    o1.x = fmaf(h1.x - y.x * inv4S, at4.x, in4.x);
    o1.y = fmaf(h1.y - y.y * inv4S, at4.y, in4.y);
    o1.z = fmaf(h1.z - y.z * inv4S, at4.z, in4.z);
    o1.w = fmaf(h1.w - y.w * inv4S, at4.w, in4.w);
    nt_store4(&outb[(size_t)(2 * j) * D], o0);
    nt_store4(&outb[(size_t)(2 * j + 1) * D], o1);
  }
}

extern "C" void kernel_launch(void* const* d_in, const int* in_sizes, int n_in,
                              void* d_out, int out_size, void* d_ws, size_t ws_size,
                              hipStream_t stream) {
  const float* level0 = (const float*)d_in[0];
  const float* level1 = (const float*)d_in[1];
  const float* level2 = (const float*)d_in[2];
  const float* level3 = (const float*)d_in[3];
  const float* w1  = (const float*)d_in[4];
  const float* b1  = (const float*)d_in[5];
  const float* w2  = (const float*)d_in[6];
  const float* b2  = (const float*)d_in[7];
  const float* wi0 = (const float*)d_in[8];
  const float* bi0 = (const float*)d_in[9];
  const float* wi1 = (const float*)d_in[10];
  const float* bi1 = (const float*)d_in[11];
  const float* wi2 = (const float*)d_in[12];
  const float* bi2 = (const float*)d_in[13];

  float* ws   = (float*)d_ws;
  float* part = ws + OFF_PART;
  float* attn = ws + OFF_ATTN;
  float* inj  = ws + OFF_INJ;

  float* out0 = (float*)d_out;                       // (32,2048,512)
  float* out1 = out0 + (size_t)B * 2048 * D;         // (32,1024,512)
  float* out2 = out1 + (size_t)B * 1024 * D;         // (32, 512,512)
  float* out3 = out2 + (size_t)B * 512 * D;          // (32, 256,512)

  k_tda<<<dim3(64, B), 512, 0, stream>>>(level0, part);
  k_weights<<<B, 512, 0, stream>>>(part, w1, b1, w2, b2, wi0, bi0, wi1, bi1, wi2, bi2,
                                   attn, inj);

  k_interp<1024, 512, false><<<dim3(32, B), 512, 0, stream>>>(
      level1, level0, attn, inj + 0ull * B * D, out0, nullptr);
  k_interp<512, 512, false><<<dim3(32, B), 512, 0, stream>>>(
      level2, level1, attn, inj + 1ull * B * D, out1, nullptr);
  k_interp<256, 256, true><<<dim3(32, B), 256, 0, stream>>>(
      level3, level2, attn, inj + 2ull * B * D, out2, out3);
}

// Round 14
// 266.768 us; speedup vs baseline: 1.1973x; 1.1973x over previous
//
#include <hip/hip_runtime.h>
#include <math.h>

constexpr int B  = 32;
constexpr int T0 = 2048;
constexpr int D  = 512;

// ws layout (in floats)
constexpr size_t OFF_PART = 0;                              // B*64*8 per-block TDA partials
constexpr size_t OFF_ATTN = OFF_PART + (size_t)B * 64 * 8;  // B*D
constexpr size_t OFF_INJ  = OFF_ATTN + (size_t)B * D;       // 3*B*D

typedef float nfloat4 __attribute__((ext_vector_type(4)));  // native vec for nt builtins

template<int LO>
__device__ __forceinline__ void wredt_add(float& v) {
  #pragma unroll
  for (int off = 32; off >= LO; off >>= 1) v += __shfl_down(v, off);
}
template<int LO>
__device__ __forceinline__ void wredt_min(float& v) {
  #pragma unroll
  for (int off = 32; off >= LO; off >>= 1) v = fminf(v, __shfl_down(v, off));
}
template<int LO>
__device__ __forceinline__ void wredt_max(float& v) {
  #pragma unroll
  for (int off = 32; off >= LO; off >>= 1) v = fmaxf(v, __shfl_down(v, off));
}
__device__ __forceinline__ void wred_add(float& v) { wredt_add<4>(v); }

__device__ __forceinline__ void nt_store4(float* p, float4 v) {
  nfloat4 nv;
  nv.x = v.x; nv.y = v.y; nv.z = v.z; nv.w = v.w;
  __builtin_nontemporal_store(nv, (nfloat4*)p);
}

// complex helpers on float4 = two interleaved complex numbers
__device__ __forceinline__ float4 cadd(float4 a, float4 b) {
  return make_float4(a.x+b.x, a.y+b.y, a.z+b.z, a.w+b.w);
}
__device__ __forceinline__ float4 csub(float4 a, float4 b) {
  return make_float4(a.x-b.x, a.y-b.y, a.z-b.z, a.w-b.w);
}
__device__ __forceinline__ float4 cmul(float4 v, float2 w) {    // v * w
  return make_float4(v.x*w.x - v.y*w.y, v.x*w.y + v.y*w.x,
                     v.z*w.x - v.w*w.y, v.z*w.y + v.w*w.x);
}
__device__ __forceinline__ float4 cmulc(float4 v, float2 w) {   // v * conj(w)
  return make_float4(v.x*w.x + v.y*w.y, v.y*w.x - v.x*w.y,
                     v.z*w.x + v.w*w.y, v.w*w.x - v.z*w.y);
}
__device__ __forceinline__ float4 cmul_mi(float4 v) {           // v * (-i)
  return make_float4(v.y, -v.x, v.w, -v.z);
}
__device__ __forceinline__ float4 cmul_pi(float4 v) {           // v * (+i)
  return make_float4(-v.y, v.x, -v.w, v.z);
}

#define R8C 0.70710678118654752f

// radix-8 DIF: x[m] at stride-Q positions; tA/tB/tC = stage twiddles.
__device__ __forceinline__ void r8_fwd(float4 x[8], float2 tA, float2 tB, float2 tC) {
  float4 a0 = cadd(x[0], x[4]), a1 = cadd(x[1], x[5]);
  float4 a2 = cadd(x[2], x[6]), a3 = cadd(x[3], x[7]);
  float4 b0 = cmul(csub(x[0], x[4]), tA);
  float4 b1 = cmul(cmul(csub(x[1], x[5]), tA), make_float2(R8C, -R8C));
  float4 b2 = cmul_mi(cmul(csub(x[2], x[6]), tA));
  float4 b3 = cmul(cmul(csub(x[3], x[7]), tA), make_float2(-R8C, -R8C));
  float4 p0 = cadd(a0, a2), p1 = cmul(csub(a0, a2), tB);
  float4 p2 = cadd(a1, a3), p3 = cmul_mi(cmul(csub(a1, a3), tB));
  x[0] = cadd(p0, p2); x[1] = cmul(csub(p0, p2), tC);
  x[2] = cadd(p1, p3); x[3] = cmul(csub(p1, p3), tC);
  float4 q0 = cadd(b0, b2), q1 = cmul(csub(b0, b2), tB);
  float4 q2 = cadd(b1, b3), q3 = cmul_mi(cmul(csub(b1, b3), tB));
  x[4] = cadd(q0, q2); x[5] = cmul(csub(q0, q2), tC);
  x[6] = cadd(q1, q3); x[7] = cmul(csub(q1, q3), tC);
}

// radix-8 DIT inverse (sign +1): x[m] at stride-h; wA/wB/wC conj-applied.
__device__ __forceinline__ void r8_inv(float4 x[8], float2 wA, float2 wB, float2 wC) {
  float4 t1 = cmulc(x[1], wA); float4 u0 = cadd(x[0], t1), u1 = csub(x[0], t1);
  float4 t3 = cmulc(x[3], wA); float4 u2 = cadd(x[2], t3), u3 = csub(x[2], t3);
  float4 t5 = cmulc(x[5], wA); float4 u4 = cadd(x[4], t5), u5 = csub(x[4], t5);
  float4 t7 = cmulc(x[7], wA); float4 u6 = cadd(x[6], t7), u7 = csub(x[6], t7);
  float4 s2 = cmulc(u2, wB), s3 = cmul_pi(cmulc(u3, wB));
  float4 y0 = cadd(u0, s2), y1 = cadd(u1, s3), y2 = csub(u0, s2), y3 = csub(u1, s3);
  float4 s6 = cmulc(u6, wB), s7 = cmul_pi(cmulc(u7, wB));
  float4 y4 = cadd(u4, s6), y5 = cadd(u5, s7), y6 = csub(u4, s6), y7 = csub(u5, s7);
  float4 c0 = cmulc(y4, wC);
  float4 c1 = cmul(cmulc(y5, wC), make_float2(R8C, R8C));
  float4 c2 = cmul_pi(cmulc(y6, wC));
  float4 c3 = cmul(cmulc(y7, wC), make_float2(-R8C, R8C));
  x[0] = cadd(y0, c0); x[1] = cadd(y1, c1); x[2] = cadd(y2, c2); x[3] = cadd(y3, c3);
  x[4] = csub(y0, c0); x[5] = csub(y1, c1); x[6] = csub(y2, c2); x[7] = csub(y3, c3);
}

// ---- fused TDA: stats + spectral centroid. Block = (b, 8 consecutive d's) ----
__global__ __launch_bounds__(512) void k_tda(const float* __restrict__ x,
                                              float* __restrict__ part) {
  __shared__ float4 buf[T0 * 2];           // [t][2 quads]; quad f = cols 4f..4f+3
  __shared__ float2 tw[1024];              // e^{-i pi k/1024}; overlaid by scratch first
  __shared__ float perd[8][8];             // per-d features (this block's 8 d's)
  float* scr = (float*)tw;                 // wave-partial scratch
  const int tid  = threadIdx.x;
  // pairing swizzle: partner blocks (same 64B line) differ by 8 in flat ID
  const int L = blockIdx.x + 64 * blockIdx.y;   // grid (64, 32)
  const int m = (L >> 3) & 1;
  const int q = (L & 7) | ((L >> 4) << 3);      // 0..1023
  const int eb = (q & 31) * 2 + m;              // 0..63 (8 d's each)
  const int b  = q >> 5;                        // 0..31
  const int f    = tid & 1;                // quad 0..1
  const int rIdx = tid >> 1;               // 0..255
  const int lane = tid & 63;
  const int wv   = tid >> 6;               // 0..7
  const float* base = x + (size_t)b * T0 * D + eb * 8 + f * 4;

  // ---- load + in-register stats ----
  float4 s1 = {0,0,0,0}, s2 = {0,0,0,0}, st = {0,0,0,0};
  float4 mn = {INFINITY,INFINITY,INFINITY,INFINITY};
  float4 mx = {-INFINITY,-INFINITY,-INFINITY,-INFINITY};
  #pragma unroll
  for (int u = 0; u < 8; ++u) {
    int t = rIdx + 256 * u;
    float4 v = *(const float4*)&base[(size_t)t * D];
    buf[t * 2 + f] = v;
    float tf = (float)t;
    s1.x += v.x; s1.y += v.y; s1.z += v.z; s1.w += v.w;
    s2.x = fmaf(v.x,v.x,s2.x); s2.y = fmaf(v.y,v.y,s2.y);
    s2.z = fmaf(v.z,v.z,s2.z); s2.w = fmaf(v.w,v.w,s2.w);
    st.x = fmaf(tf,v.x,st.x); st.y = fmaf(tf,v.y,st.y);
    st.z = fmaf(tf,v.z,st.z); st.w = fmaf(tf,v.w,st.w);
    mn.x = fminf(mn.x,v.x); mn.y = fminf(mn.y,v.y); mn.z = fminf(mn.z,v.z); mn.w = fminf(mn.w,v.w);
    mx.x = fmaxf(mx.x,v.x); mx.y = fmaxf(mx.y,v.y); mx.z = fmaxf(mx.z,v.z); mx.w = fmaxf(mx.w,v.w);
  }
  __syncthreads();
  // lag-1 cross terms from LDS
  float4 cc = {0,0,0,0};
  #pragma unroll
  for (int u = 0; u < 8; ++u) {
    int t = rIdx + 256 * u;
    if (t < T0 - 1) {
      float4 a = buf[t * 2 + f];
      float4 nb = buf[(t + 1) * 2 + f];
      cc.x = fmaf(a.x,nb.x,cc.x); cc.y = fmaf(a.y,nb.y,cc.y);
      cc.z = fmaf(a.z,nb.z,cc.z); cc.w = fmaf(a.w,nb.w,cc.w);
    }
  }
  wredt_add<2>(s1.x); wredt_add<2>(s1.y); wredt_add<2>(s1.z); wredt_add<2>(s1.w);
  wredt_add<2>(s2.x); wredt_add<2>(s2.y); wredt_add<2>(s2.z); wredt_add<2>(s2.w);
  wredt_add<2>(st.x); wredt_add<2>(st.y); wredt_add<2>(st.z); wredt_add<2>(st.w);
  wredt_add<2>(cc.x); wredt_add<2>(cc.y); wredt_add<2>(cc.z); wredt_add<2>(cc.w);
  wredt_min<2>(mn.x); wredt_min<2>(mn.y); wredt_min<2>(mn.z); wredt_min<2>(mn.w);
  wredt_max<2>(mx.x); wredt_max<2>(mx.y); wredt_max<2>(mx.z); wredt_max<2>(mx.w);
  if (lane < 2) {                           // lane == f here
    float* p = scr + ((size_t)wv * 2 + f) * 24;
    p[0]=s1.x; p[1]=s2.x; p[2]=st.x; p[3]=cc.x; p[4]=mn.x; p[5]=mx.x;
    p[6]=s1.y; p[7]=s2.y; p[8]=st.y; p[9]=cc.y; p[10]=mn.y; p[11]=mx.y;
    p[12]=s1.z; p[13]=s2.z; p[14]=st.z; p[15]=cc.z; p[16]=mn.z; p[17]=mx.z;
    p[18]=s1.w; p[19]=s2.w; p[20]=st.w; p[21]=cc.w; p[22]=mn.w; p[23]=mx.w;
  }
  __syncthreads();
  if (tid < 8) {
    const int dl = tid;                     // 0..7 local d
    const int fq = dl >> 2, c = dl & 3;
    float S1=0.f, S2=0.f, St=0.f, C=0.f, MN=INFINITY, MX=-INFINITY;
    for (int w = 0; w < 8; ++w) {
      const float* p = scr + ((size_t)w * 2 + fq) * 24 + c * 6;
      S1 += p[0]; S2 += p[1]; St += p[2]; C += p[3];
      MN = fminf(MN, p[4]); MX = fmaxf(MX, p[5]);
    }
    const float x0 = ((const float*)buf)[dl];
    const float xl = ((const float*)buf)[(size_t)(T0 - 1) * 8 + dl];
    const float Tf = (float)T0;
    const float mean = S1 / Tf;
    const float sxx  = S2 - S1 * S1 / Tf;
    const float stdv = sqrtf(fmaxf(sxx / (Tf - 1.f), 0.f));
    const float tbar = (Tf - 1.f) * 0.5f;
    const float Sic  = Tf * (Tf * Tf - 1.f) / 12.f;
    float trend = (St - tbar * S1) / sqrtf(sxx * Sic);
    if (isnan(trend)) trend = 0.f;
    const float na = Tf - 1.f;
    const float Sa = S1 - xl, Sb = S1 - x0;
    const float an  = C - Sa * Sb / na;
    const float sa2 = (S2 - xl * xl) - Sa * Sa / na;
    const float sb2 = (S2 - x0 * x0) - Sb * Sb / na;
    float ac = an / sqrtf(sa2 * sb2);
    if (isnan(ac)) ac = 0.f;
    perd[dl][0] = mean; perd[dl][1] = stdv; perd[dl][2] = MN;
    perd[dl][3] = MX;   perd[dl][4] = trend; perd[dl][5] = ac;
  }
  __syncthreads();   // scr reads done -> tw may be overwritten

  // ---- twiddles ----
  for (int k = tid; k < 1024; k += 512) {
    float sw, cw;
    sincosf(-(float)M_PI * (float)k * (1.0f / 1024.0f), &sw, &cw);
    tw[k] = make_float2(cw, sw);
  }
  __syncthreads();

  // ---- in-place DIF FFT, 2048-pt: 3 radix-8 passes + 1 radix-4 (unit) ----
  for (int stg = 0; stg < 9; stg += 3) {
    const int qsh = 8 - stg;            // log2(Q)
    const int Q = 1 << qsh;
    int pp = tid & 1;
    int gi = tid >> 1;                  // 0..255
    int j3 = gi & (Q - 1);
    int g  = gi >> qsh;
    int bs = (g << (qsh + 3)) + j3;
    float2 tA = tw[j3 << stg];
    float2 tB = tw[j3 << (stg + 1)];
    float2 tC = tw[j3 << (stg + 2)];
    float4 xx[8];
    #pragma unroll
    for (int mm = 0; mm < 8; ++mm) xx[mm] = buf[(bs + mm * Q) * 2 + pp];
    r8_fwd(xx, tA, tB, tC);
    #pragma unroll
    for (int mm = 0; mm < 8; ++mm) buf[(bs + mm * Q) * 2 + pp] = xx[mm];
    __syncthreads();
  }
  // tail radix-4 (stages 9,10; unit twiddles)
  #pragma unroll
  for (int it = 0; it < 2; ++it) {
    int sl = it * 512 + tid;
    int pp = sl & 1;
    int qi = sl >> 1;                   // 0..511
    int bs = qi << 2;
    float4 x0 = buf[bs*2+pp], x1 = buf[(bs+1)*2+pp];
    float4 x2 = buf[(bs+2)*2+pp], x3 = buf[(bs+3)*2+pp];
    float4 u0 = cadd(x0, x2);
    float4 t2 = csub(x0, x2);
    float4 u1 = cadd(x1, x3);
    float4 t3 = cmul_mi(csub(x1, x3));
    buf[bs*2+pp]     = cadd(u0, u1);
    buf[(bs+1)*2+pp] = csub(u0, u1);
    buf[(bs+2)*2+pp] = cadd(t2, t3);
    buf[(bs+3)*2+pp] = csub(t2, t3);
  }
  __syncthreads();
  // buf[p] = Z[rev11(p)]

  // ---- centroid: unpack real spectra per column, k = 0..1023 ----
  float4 num = {0,0,0,0}, den = {0,0,0,0};
  #pragma unroll
  for (int it = 0; it < 4; ++it) {
    int sl = it * 512 + tid;
    int pp = sl & 1;
    int k = sl >> 1;
    int p1 = __brev((unsigned)k) >> 21;
    int p2 = __brev((unsigned)((T0 - k) & (T0 - 1))) >> 21;
    float4 zk = buf[p1 * 2 + pp];
    float4 zm = buf[p2 * 2 + pp];
    float kf = (float)k;
    float arx = 0.5f*(zk.x+zm.x), ary = 0.5f*(zk.y-zm.y);
    float brx = 0.5f*(zk.y+zm.y), bry = 0.5f*(zm.x-zk.x);
    float pa = arx*arx + ary*ary, pb = brx*brx + bry*bry;
    num.x = fmaf(kf, pa, num.x); den.x += pa;
    num.y = fmaf(kf, pb, num.y); den.y += pb;
    arx = 0.5f*(zk.z+zm.z); ary = 0.5f*(zk.w-zm.w);
    brx = 0.5f*(zk.w+zm.w); bry = 0.5f*(zm.z-zk.z);
    pa = arx*arx + ary*ary; pb = brx*brx + bry*bry;
    num.z = fmaf(kf, pa, num.z); den.z += pa;
    num.w = fmaf(kf, pb, num.w); den.w += pb;
  }
  wredt_add<2>(num.x); wredt_add<2>(num.y); wredt_add<2>(num.z); wredt_add<2>(num.w);
  wredt_add<2>(den.x); wredt_add<2>(den.y); wredt_add<2>(den.z); wredt_add<2>(den.w);
  if (lane < 2) {
    float* p = scr + ((size_t)wv * 2 + f) * 8;
    p[0]=num.x; p[1]=num.y; p[2]=num.z; p[3]=num.w;
    p[4]=den.x; p[5]=den.y; p[6]=den.z; p[7]=den.w;
  }
  __syncthreads();
  if (tid < 8) {
    const int dl = tid;
    const int fq = dl >> 2, c = dl & 3;
    float N = 0.f, Dn = 0.f;
    for (int w = 0; w < 8; ++w) {
      const float* p = scr + ((size_t)w * 2 + fq) * 8;
      N += p[c]; Dn += p[4 + c];
    }
    float cent = N / Dn;
    if (isnan(cent)) cent = 0.f;
    perd[dl][6] = cent;
  }
  __syncthreads();
  if (tid < 7) {
    float s = 0.f;
    #pragma unroll
    for (int dl = 0; dl < 8; ++dl) s += perd[dl][tid];
    part[((size_t)b * 64 + eb) * 8 + tid] = s;
  }
}

// --------------- attn = sigmoid(relu(tda@w1+b1)@w2+b2); inj_l -----------------
__global__ __launch_bounds__(512) void k_weights(const float* __restrict__ part,
    const float* __restrict__ w1, const float* __restrict__ b1,
    const float* __restrict__ w2, const float* __restrict__ b2,
    const float* __restrict__ wi0, const float* __restrict__ bi0,
    const float* __restrict__ wi1, const float* __restrict__ bi1,
    const float* __restrict__ wi2, const float* __restrict__ bi2,
    float* __restrict__ attn, float* __restrict__ inj) {
  const int b = blockIdx.x;
  const int j = threadIdx.x;
  __shared__ float td[7];
  __shared__ float h[512];
  if (j < 7) {
    float s = 0.f;
    for (int w = 0; w < 64; ++w) s += part[((size_t)b * 64 + w) * 8 + j];
    td[j] = s * (1.0f / (float)D);
  }
  __syncthreads();
  float a = b1[j];
  #pragma unroll
  for (int f = 0; f < 7; ++f) a = fmaf(td[f], w1[f * D + j], a);
  h[j] = fmaxf(a, 0.0f);
  __syncthreads();
  float a2 = b2[j];
  for (int k = 0; k < D; ++k) a2 = fmaf(h[k], w2[k * D + j], a2);
  attn[(size_t)b * D + j] = 1.0f / (1.0f + expf(-a2));
  const float* wis[3] = {wi0, wi1, wi2};
  const float* bis[3] = {bi0, bi1, bi2};
  #pragma unroll
  for (int l = 0; l < 3; ++l) {
    float ai = bis[l][j];
    #pragma unroll
    for (int f = 0; f < 7; ++f) ai = fmaf(td[f], wis[l][f * D + j], ai);
    inj[(size_t)l * B * D + (size_t)b * D + j] = 0.3f * ai;
  }
}

// --------- FFT 2x spectral interp body (NT=512 fixed), batched 8 pairs -------
// Plain cached loads (R13 lesson: nt-loads demote L3 hits). nt-stores only.
template<int S, bool COPY>
__device__ __forceinline__ void interp_body(int bb,
    const float* __restrict__ low, const float* __restrict__ high,
    const float* __restrict__ attn, const float* __restrict__ inj,
    float* __restrict__ out, float* __restrict__ copy_out,
    float4* buf, float2* tw, float4 (*scrA)[4], float4* Zh4) {
  constexpr int NT = 512;
  constexpr int LOG2S = (S == 1024) ? 10 : (S == 512) ? 9 : 8;
  constexpr int WAVES = NT / 64;
  constexpr int RPT   = S / (NT / 4);          // rows per thread
  constexpr int R8IT  = S / 2;                 // items per radix-8 pass
  const int tid  = threadIdx.x;
  // pairing swizzle within segment: partner blocks differ by 8 in flat ID
  const int m = (bb >> 3) & 1;
  const int q = (bb & 7) | ((bb >> 4) << 3);   // 0..511
  const int eb = (q & 15) * 2 + m;             // 0..31
  const int b  = q >> 4;                       // 0..31
  const int f    = tid & 3;
  const int rIdx = tid >> 2;
  const int lane = tid & 63;
  const int wv   = tid >> 6;
  const int d0   = eb * 16;

  const float* lowb  = low  + (size_t)b * S * D + d0 + 4 * f;
  const float* highb = high + (size_t)b * (2 * S) * D + d0 + 4 * f;
  float*       outb  = out  + (size_t)b * (2 * S) * D + d0 + 4 * f;
  float*       cpb   = COPY ? copy_out + (size_t)b * S * D + d0 + 4 * f : nullptr;

  // ---- load + z in regs + alternating-sum partials ----
  float4 zreg[RPT];
  float4 acc = {0,0,0,0};
  #pragma unroll
  for (int u = 0; u < RPT; ++u) {
    int t = rIdx + (NT / 4) * u;
    float4 v = *(const float4*)&lowb[(size_t)t * D];
    zreg[u] = v;
    buf[t * 4 + f] = v;
    if (COPY) nt_store4(&cpb[(size_t)t * D], v);
    acc.x += v.x; acc.y += v.y; acc.z += v.z; acc.w += v.w;
  }
  if (rIdx & 1) { acc.x = -acc.x; acc.y = -acc.y; acc.z = -acc.z; acc.w = -acc.w; }
  for (int k = tid; k < S; k += NT) {
    float sw, cw;
    sincosf(-(float)M_PI * (float)k * (1.0f / (float)S), &sw, &cw);
    tw[k] = make_float2(cw, sw);
  }
  wred_add(acc.x); wred_add(acc.y); wred_add(acc.z); wred_add(acc.w);
  if (lane < 4) scrA[wv][f] = acc;             // f == lane
  __syncthreads();
  if (tid < 4) {
    float4 s = scrA[0][tid];
    for (int w = 1; w < WAVES; ++w) {
      float4 qv = scrA[w][tid];
      s.x += qv.x; s.y += qv.y; s.z += qv.z; s.w += qv.w;
    }
    Zh4[tid] = s;
  }
  __syncthreads();

  const float inv4S = 1.0f / (4.0f * (float)S);
  const float4 at4 = *(const float4*)&attn[(size_t)b * D + d0 + 4 * f];
  const float4 in4 = *(const float4*)&inj [(size_t)b * D + d0 + 4 * f];
  float4 Zs = Zh4[f];
  Zs.x *= inv4S; Zs.y *= inv4S; Zs.z *= inv4S; Zs.w *= inv4S;

  // ---- forward DIF (natural -> bitrev), radix-8 passes ----
  for (int stg = 0; stg + 2 < LOG2S; stg += 3) {
    const int qsh = LOG2S - 3 - stg;
    const int Q = 1 << qsh;
    #pragma unroll
    for (int it = 0; it < (R8IT + NT - 1) / NT; ++it) {
      int sl = it * NT + tid;
      if (sl < R8IT) {
        int pp = sl & 3;
        int gi = sl >> 2;
        int j3 = gi & (Q - 1);
        int g  = gi >> qsh;
        int bs = (g << (qsh + 3)) + j3;
        float2 tA = tw[j3 << (stg + 1)];
        float2 tB = tw[j3 << (stg + 2)];
        float2 tC = tw[j3 << (stg + 3)];
        float4 xx[8];
        #pragma unroll
        for (int mm = 0; mm < 8; ++mm) xx[mm] = buf[(bs + mm * Q) * 4 + pp];
        r8_fwd(xx, tA, tB, tC);
        #pragma unroll
        for (int mm = 0; mm < 8; ++mm) buf[(bs + mm * Q) * 4 + pp] = xx[mm];
      }
      __syncthreads();
    }
  }
  if (LOG2S % 3 == 1) {                  // tail radix-2 (unit twiddles)
    #pragma unroll
    for (int it = 0; it < (2 * S) / NT; ++it) {
      int sl = it * NT + tid;
      int pp = sl & 3;
      int bi = sl >> 2;
      int i = bi * 2;
      float4 a = buf[i * 4 + pp];
      float4 c4 = buf[(i + 1) * 4 + pp];
      buf[i * 4 + pp]       = cadd(a, c4);
      buf[(i + 1) * 4 + pp] = csub(a, c4);
    }
    __syncthreads();
  }
  if (LOG2S % 3 == 2) {                  // tail radix-4 (unit twiddles), guarded
    #pragma unroll
    for (int it = 0; it < (S + NT - 1) / NT; ++it) {
      int sl = it * NT + tid;
      if (sl < S) {
        int pp = sl & 3;
        int qi = sl >> 2;
        int bs = qi << 2;
        float4 x0 = buf[bs*4+pp], x1 = buf[(bs+1)*4+pp];
        float4 x2 = buf[(bs+2)*4+pp], x3 = buf[(bs+3)*4+pp];
        float4 u0 = cadd(x0, x2);
        float4 t2 = csub(x0, x2);
        float4 u1 = cadd(x1, x3);
        float4 t3 = cmul_mi(csub(x1, x3));
        buf[bs*4+pp]     = cadd(u0, u1);
        buf[(bs+1)*4+pp] = csub(u0, u1);
        buf[(bs+2)*4+pp] = cadd(t2, t3);
        buf[(bs+3)*4+pp] = csub(t2, t3);
      }
    }
    __syncthreads();
  }
  // buf[p] = Z[rev(p)]

  // ---- inverse DIT (bitrev -> natural), radix-8 passes; g fused in pass 0 ----
  for (int stg = 0; stg + 2 < LOG2S; stg += 3) {
    const int h = 1 << stg;
    #pragma unroll
    for (int it = 0; it < (R8IT + NT - 1) / NT; ++it) {
      int sl = it * NT + tid;
      if (sl < R8IT) {
        int pp = sl & 3;
        int gi = sl >> 2;
        int j  = gi & (h - 1);
        int G  = gi >> stg;
        int bs = (G << (stg + 3)) + j;
        float2 wA = tw[j << (LOG2S - stg)];
        float2 wB = tw[j << (LOG2S - stg - 1)];
        float2 wC = tw[j << (LOG2S - stg - 2)];
        float4 xx[8];
        if (stg == 0) {
          #pragma unroll
          for (int mm = 0; mm < 8; ++mm) {
            int p = bs + mm;
            int k = __brev((unsigned)p) >> (32 - LOG2S);
            float2 w = tw[k];
            float sgn = (k < S / 2) ? 1.f : (k == S / 2) ? 0.f : -1.f;
            float4 v = cmulc(buf[p * 4 + pp], w);
            v.x *= sgn; v.y *= sgn; v.z *= sgn; v.w *= sgn;
            xx[mm] = v;
          }
        } else {
          #pragma unroll
          for (int mm = 0; mm < 8; ++mm) xx[mm] = buf[(bs + mm * h) * 4 + pp];
        }
        r8_inv(xx, wA, wB, wC);
        #pragma unroll
        for (int mm = 0; mm < 8; ++mm) buf[(bs + mm * h) * 4 + pp] = xx[mm];
      }
      __syncthreads();
    }
  }
  if (LOG2S % 3 == 1) {                  // tail radix-2 at stg = LOG2S-1
    const int stg = LOG2S - 1;
    const int h = 1 << stg;
    #pragma unroll
    for (int it = 0; it < (2 * S) / NT; ++it) {
      int sl = it * NT + tid;
      int pp = sl & 3;
      int bi = sl >> 2;
      int j = bi & (h - 1);
      int g = bi >> stg;
      int i = (g << (stg + 1)) + j;
      float2 w = tw[j << (LOG2S - stg)];
      float4 a = buf[i * 4 + pp];
      float4 v = buf[(i + h) * 4 + pp];
      float4 t = cmulc(v, w);
      buf[i * 4 + pp]       = cadd(a, t);
      buf[(i + h) * 4 + pp] = csub(a, t);
    }
    __syncthreads();
  }
  if (LOG2S % 3 == 2) {                  // tail radix-4 at stg = LOG2S-2, guarded
    const int stg = LOG2S - 2;
    const int h = 1 << stg;
    #pragma unroll
    for (int it = 0; it < (S + NT - 1) / NT; ++it) {
      int sl = it * NT + tid;
      if (sl < S) {
        int pp = sl & 3;
        int qi = sl >> 2;
        int j = qi & (h - 1);
        int g = qi >> stg;
        int bs = (g << (stg + 2)) + j;
        float2 wA = tw[j << (LOG2S - stg)];
        float2 wB = tw[j << (LOG2S - stg - 1)];
        float4 x0 = buf[bs * 4 + pp];
        float4 x1 = buf[(bs + h) * 4 + pp];
        float4 x2 = buf[(bs + 2 * h) * 4 + pp];
        float4 x3 = buf[(bs + 3 * h) * 4 + pp];
        float4 t1 = cmulc(x1, wA);
        float4 u0 = cadd(x0, t1), u1 = csub(x0, t1);
        float4 t3 = cmulc(x3, wA);
        float4 u2 = cadd(x2, t3), u3 = csub(x2, t3);
        float4 s2c = cmulc(u2, wB);
        float4 s3c = cmul_pi(cmulc(u3, wB));
        buf[bs * 4 + pp]           = cadd(u0, s2c);
        buf[(bs + h) * 4 + pp]     = cadd(u1, s3c);
        buf[(bs + 2 * h) * 4 + pp] = csub(u0, s2c);
        buf[(bs + 3 * h) * 4 + pp] = csub(u1, s3c);
      }
    }
    __syncthreads();
  }

  // ---- even + odd outputs together (adjacent row pairs), nt-stored ----
  #pragma unroll
  for (int u = 0; u < RPT; ++u) {
    int j = rIdx + (NT / 4) * u;
    float4 z = zreg[u];
    float sg = (j & 1) ? -1.f : 1.f;
    float4 res_e;
    res_e.x = fmaf(0.25f, z.x, sg * Zs.x);
    res_e.y = fmaf(0.25f, z.y, sg * Zs.y);
    res_e.z = fmaf(0.25f, z.z, sg * Zs.z);
    res_e.w = fmaf(0.25f, z.w, sg * Zs.w);
    float4 y = buf[j * 4 + f];
    float4 h0 = *(const float4*)&highb[(size_t)(2 * j) * D];
    float4 h1 = *(const float4*)&highb[(size_t)(2 * j + 1) * D];
    float4 o0, o1;
    o0.x = fmaf(h0.x - res_e.x, at4.x, in4.x);
    o0.y = fmaf(h0.y - res_e.y, at4.y, in4.y);
    o0.z = fmaf(h0.z - res_e.z, at4.z, in4.z);
    o0.w = fmaf(h0.w - res_e.w, at4.w, in4.w);
    o1.x = fmaf(h1.x - y.x * inv4S, at4.x, in4.x);
    o1.y = fmaf(h1.y - y.y * inv4S, at4.y, in4.y);
    o1.z = fmaf(h1.z - y.z * inv4S, at4.z, in4.z);
    o1.w = fmaf(h1.w - y.w * inv4S, at4.w, in4.w);
    nt_store4(&outb[(size_t)(2 * j) * D], o0);
    nt_store4(&outb[(size_t)(2 * j + 1) * D], o1);
  }
}

// ---- merged interp launch: 3072 blocks, segment per level (1024 first) ------
__global__ __launch_bounds__(512) void k_interp_all(
    const float* __restrict__ l0, const float* __restrict__ l1,
    const float* __restrict__ l2, const float* __restrict__ l3,
    const float* __restrict__ attn, const float* __restrict__ inj,
    float* __restrict__ out0, float* __restrict__ out1,
    float* __restrict__ out2, float* __restrict__ out3) {
  __shared__ float4 buf[4096];          // 64 KB (max variant S=1024)
  __shared__ float2 tw[1024];           // 8 KB
  __shared__ float4 scrA[8][4];
  __shared__ float4 Zh4[4];
  const int gb = blockIdx.x;
  if (gb < 1024) {
    interp_body<1024, false>(gb, l1, l0, attn, inj + 0ull * B * D, out0, nullptr,
                             buf, tw, scrA, Zh4);
  } else if (gb < 2048) {
    interp_body<512, false>(gb - 1024, l2, l1, attn, inj + 1ull * B * D, out1,
                            nullptr, buf, tw, scrA, Zh4);
  } else {
    interp_body<256, true>(gb - 2048, l3, l2, attn, inj + 2ull * B * D, out2,
                           out3, buf, tw, scrA, Zh4);
  }
}

extern "C" void kernel_launch(void* const* d_in, const int* in_sizes, int n_in,
                              void* d_out, int out_size, void* d_ws, size_t ws_size,
                              hipStream_t stream) {
  const float* level0 = (const float*)d_in[0];
  const float* level1 = (const float*)d_in[1];
  const float* level2 = (const float*)d_in[2];
  const float* level3 = (const float*)d_in[3];
  const float* w1  = (const float*)d_in[4];
  const float* b1  = (const float*)d_in[5];
  const float* w2  = (const float*)d_in[6];
  const float* b2  = (const float*)d_in[7];
  const float* wi0 = (const float*)d_in[8];
  const float* bi0 = (const float*)d_in[9];
  const float* wi1 = (const float*)d_in[10];
  const float* bi1 = (const float*)d_in[11];
  const float* wi2 = (const float*)d_in[12];
  const float* bi2 = (const float*)d_in[13];

  float* ws   = (float*)d_ws;
  float* part = ws + OFF_PART;
  float* attn = ws + OFF_ATTN;
  float* inj  = ws + OFF_INJ;

  float* out0 = (float*)d_out;                       // (32,2048,512)
  float* out1 = out0 + (size_t)B * 2048 * D;         // (32,1024,512)
  float* out2 = out1 + (size_t)B * 1024 * D;         // (32, 512,512)
  float* out3 = out2 + (size_t)B * 512 * D;          // (32, 256,512)

  k_tda<<<dim3(64, B), 512, 0, stream>>>(level0, part);
  k_weights<<<B, 512, 0, stream>>>(part, w1, b1, w2, b2, wi0, bi0, wi1, bi1, wi2, bi2,
                                   attn, inj);
  k_interp_all<<<3072, 512, 0, stream>>>(level0, level1, level2, level3,
                                         attn, inj, out0, out1, out2, out3);
}

// Round 15
// 257.737 us; speedup vs baseline: 1.2392x; 1.0350x over previous
//
#include <hip/hip_runtime.h>
#include <math.h>

constexpr int B  = 32;
constexpr int T0 = 2048;
constexpr int D  = 512;

// ws layout (in floats)
constexpr size_t OFF_PART = 0;                              // B*64*8 per-block TDA partials
constexpr size_t OFF_ATTN = OFF_PART + (size_t)B * 64 * 8;  // B*D
constexpr size_t OFF_INJ  = OFF_ATTN + (size_t)B * D;       // 3*B*D

typedef float nfloat4 __attribute__((ext_vector_type(4)));  // native vec for nt builtins

template<int LO>
__device__ __forceinline__ void wredt_add(float& v) {
  #pragma unroll
  for (int off = 32; off >= LO; off >>= 1) v += __shfl_down(v, off);
}
template<int LO>
__device__ __forceinline__ void wredt_min(float& v) {
  #pragma unroll
  for (int off = 32; off >= LO; off >>= 1) v = fminf(v, __shfl_down(v, off));
}
template<int LO>
__device__ __forceinline__ void wredt_max(float& v) {
  #pragma unroll
  for (int off = 32; off >= LO; off >>= 1) v = fmaxf(v, __shfl_down(v, off));
}
__device__ __forceinline__ void wred_add(float& v) { wredt_add<4>(v); }

__device__ __forceinline__ void nt_store4(float* p, float4 v) {
  nfloat4 nv;
  nv.x = v.x; nv.y = v.y; nv.z = v.z; nv.w = v.w;
  __builtin_nontemporal_store(nv, (nfloat4*)p);
}

// complex helpers on float4 = two interleaved complex numbers
__device__ __forceinline__ float4 cadd(float4 a, float4 b) {
  return make_float4(a.x+b.x, a.y+b.y, a.z+b.z, a.w+b.w);
}
__device__ __forceinline__ float4 csub(float4 a, float4 b) {
  return make_float4(a.x-b.x, a.y-b.y, a.z-b.z, a.w-b.w);
}
__device__ __forceinline__ float4 cmul(float4 v, float2 w) {    // v * w
  return make_float4(v.x*w.x - v.y*w.y, v.x*w.y + v.y*w.x,
                     v.z*w.x - v.w*w.y, v.z*w.y + v.w*w.x);
}
__device__ __forceinline__ float4 cmulc(float4 v, float2 w) {   // v * conj(w)
  return make_float4(v.x*w.x + v.y*w.y, v.y*w.x - v.x*w.y,
                     v.z*w.x + v.w*w.y, v.w*w.x - v.z*w.y);
}
__device__ __forceinline__ float4 cmul_mi(float4 v) {           // v * (-i)
  return make_float4(v.y, -v.x, v.w, -v.z);
}
__device__ __forceinline__ float4 cmul_pi(float4 v) {           // v * (+i)
  return make_float4(-v.y, v.x, -v.w, v.z);
}

#define R8C 0.70710678118654752f

// radix-8 DIF: x[m] at stride-Q positions; tA/tB/tC = stage twiddles.
__device__ __forceinline__ void r8_fwd(float4 x[8], float2 tA, float2 tB, float2 tC) {
  float4 a0 = cadd(x[0], x[4]), a1 = cadd(x[1], x[5]);
  float4 a2 = cadd(x[2], x[6]), a3 = cadd(x[3], x[7]);
  float4 b0 = cmul(csub(x[0], x[4]), tA);
  float4 b1 = cmul(cmul(csub(x[1], x[5]), tA), make_float2(R8C, -R8C));
  float4 b2 = cmul_mi(cmul(csub(x[2], x[6]), tA));
  float4 b3 = cmul(cmul(csub(x[3], x[7]), tA), make_float2(-R8C, -R8C));
  float4 p0 = cadd(a0, a2), p1 = cmul(csub(a0, a2), tB);
  float4 p2 = cadd(a1, a3), p3 = cmul_mi(cmul(csub(a1, a3), tB));
  x[0] = cadd(p0, p2); x[1] = cmul(csub(p0, p2), tC);
  x[2] = cadd(p1, p3); x[3] = cmul(csub(p1, p3), tC);
  float4 q0 = cadd(b0, b2), q1 = cmul(csub(b0, b2), tB);
  float4 q2 = cadd(b1, b3), q3 = cmul_mi(cmul(csub(b1, b3), tB));
  x[4] = cadd(q0, q2); x[5] = cmul(csub(q0, q2), tC);
  x[6] = cadd(q1, q3); x[7] = cmul(csub(q1, q3), tC);
}

// radix-8 DIT inverse (sign +1): x[m] at stride-h; wA/wB/wC conj-applied.
__device__ __forceinline__ void r8_inv(float4 x[8], float2 wA, float2 wB, float2 wC) {
  float4 t1 = cmulc(x[1], wA); float4 u0 = cadd(x[0], t1), u1 = csub(x[0], t1);
  float4 t3 = cmulc(x[3], wA); float4 u2 = cadd(x[2], t3), u3 = csub(x[2], t3);
  float4 t5 = cmulc(x[5], wA); float4 u4 = cadd(x[4], t5), u5 = csub(x[4], t5);
  float4 t7 = cmulc(x[7], wA); float4 u6 = cadd(x[6], t7), u7 = csub(x[6], t7);
  float4 s2 = cmulc(u2, wB), s3 = cmul_pi(cmulc(u3, wB));
  float4 y0 = cadd(u0, s2), y1 = cadd(u1, s3), y2 = csub(u0, s2), y3 = csub(u1, s3);
  float4 s6 = cmulc(u6, wB), s7 = cmul_pi(cmulc(u7, wB));
  float4 y4 = cadd(u4, s6), y5 = cadd(u5, s7), y6 = csub(u4, s6), y7 = csub(u5, s7);
  float4 c0 = cmulc(y4, wC);
  float4 c1 = cmul(cmulc(y5, wC), make_float2(R8C, R8C));
  float4 c2 = cmul_pi(cmulc(y6, wC));
  float4 c3 = cmul(cmulc(y7, wC), make_float2(-R8C, R8C));
  x[0] = cadd(y0, c0); x[1] = cadd(y1, c1); x[2] = cadd(y2, c2); x[3] = cadd(y3, c3);
  x[4] = csub(y0, c0); x[5] = csub(y1, c1); x[6] = csub(y2, c2); x[7] = csub(y3, c3);
}

// ---- fused TDA: stats + spectral centroid. Block = (b, 8 consecutive d's) ----
__global__ __launch_bounds__(512) void k_tda(const float* __restrict__ x,
                                              float* __restrict__ part) {
  __shared__ float4 buf[T0 * 2];           // [t][2 quads]; quad f = cols 4f..4f+3
  __shared__ float2 tw[1024];              // e^{-i pi k/1024}; overlaid by scratch first
  __shared__ float perd[8][8];             // per-d features (this block's 8 d's)
  float* scr = (float*)tw;                 // wave-partial scratch
  const int tid  = threadIdx.x;
  // pairing swizzle: partner blocks (same 64B line) differ by 8 in flat ID
  const int L = blockIdx.x + 64 * blockIdx.y;   // grid (64, 32)
  const int m = (L >> 3) & 1;
  const int q = (L & 7) | ((L >> 4) << 3);      // 0..1023
  const int eb = (q & 31) * 2 + m;              // 0..63 (8 d's each)
  const int b  = q >> 5;                        // 0..31
  const int f    = tid & 1;                // quad 0..1
  const int rIdx = tid >> 1;               // 0..255
  const int lane = tid & 63;
  const int wv   = tid >> 6;               // 0..7
  const float* base = x + (size_t)b * T0 * D + eb * 8 + f * 4;

  // ---- load + in-register stats ----
  float4 s1 = {0,0,0,0}, s2 = {0,0,0,0}, st = {0,0,0,0};
  float4 mn = {INFINITY,INFINITY,INFINITY,INFINITY};
  float4 mx = {-INFINITY,-INFINITY,-INFINITY,-INFINITY};
  #pragma unroll
  for (int u = 0; u < 8; ++u) {
    int t = rIdx + 256 * u;
    float4 v = *(const float4*)&base[(size_t)t * D];
    buf[t * 2 + f] = v;
    float tf = (float)t;
    s1.x += v.x; s1.y += v.y; s1.z += v.z; s1.w += v.w;
    s2.x = fmaf(v.x,v.x,s2.x); s2.y = fmaf(v.y,v.y,s2.y);
    s2.z = fmaf(v.z,v.z,s2.z); s2.w = fmaf(v.w,v.w,s2.w);
    st.x = fmaf(tf,v.x,st.x); st.y = fmaf(tf,v.y,st.y);
    st.z = fmaf(tf,v.z,st.z); st.w = fmaf(tf,v.w,st.w);
    mn.x = fminf(mn.x,v.x); mn.y = fminf(mn.y,v.y); mn.z = fminf(mn.z,v.z); mn.w = fminf(mn.w,v.w);
    mx.x = fmaxf(mx.x,v.x); mx.y = fmaxf(mx.y,v.y); mx.z = fmaxf(mx.z,v.z); mx.w = fmaxf(mx.w,v.w);
  }
  __syncthreads();
  // lag-1 cross terms from LDS
  float4 cc = {0,0,0,0};
  #pragma unroll
  for (int u = 0; u < 8; ++u) {
    int t = rIdx + 256 * u;
    if (t < T0 - 1) {
      float4 a = buf[t * 2 + f];
      float4 nb = buf[(t + 1) * 2 + f];
      cc.x = fmaf(a.x,nb.x,cc.x); cc.y = fmaf(a.y,nb.y,cc.y);
      cc.z = fmaf(a.z,nb.z,cc.z); cc.w = fmaf(a.w,nb.w,cc.w);
    }
  }
  wredt_add<2>(s1.x); wredt_add<2>(s1.y); wredt_add<2>(s1.z); wredt_add<2>(s1.w);
  wredt_add<2>(s2.x); wredt_add<2>(s2.y); wredt_add<2>(s2.z); wredt_add<2>(s2.w);
  wredt_add<2>(st.x); wredt_add<2>(st.y); wredt_add<2>(st.z); wredt_add<2>(st.w);
  wredt_add<2>(cc.x); wredt_add<2>(cc.y); wredt_add<2>(cc.z); wredt_add<2>(cc.w);
  wredt_min<2>(mn.x); wredt_min<2>(mn.y); wredt_min<2>(mn.z); wredt_min<2>(mn.w);
  wredt_max<2>(mx.x); wredt_max<2>(mx.y); wredt_max<2>(mx.z); wredt_max<2>(mx.w);
  if (lane < 2) {                           // lane == f here
    float* p = scr + ((size_t)wv * 2 + f) * 24;
    p[0]=s1.x; p[1]=s2.x; p[2]=st.x; p[3]=cc.x; p[4]=mn.x; p[5]=mx.x;
    p[6]=s1.y; p[7]=s2.y; p[8]=st.y; p[9]=cc.y; p[10]=mn.y; p[11]=mx.y;
    p[12]=s1.z; p[13]=s2.z; p[14]=st.z; p[15]=cc.z; p[16]=mn.z; p[17]=mx.z;
    p[18]=s1.w; p[19]=s2.w; p[20]=st.w; p[21]=cc.w; p[22]=mn.w; p[23]=mx.w;
  }
  __syncthreads();
  if (tid < 8) {
    const int dl = tid;                     // 0..7 local d
    const int fq = dl >> 2, c = dl & 3;
    float S1=0.f, S2=0.f, St=0.f, C=0.f, MN=INFINITY, MX=-INFINITY;
    for (int w = 0; w < 8; ++w) {
      const float* p = scr + ((size_t)w * 2 + fq) * 24 + c * 6;
      S1 += p[0]; S2 += p[1]; St += p[2]; C += p[3];
      MN = fminf(MN, p[4]); MX = fmaxf(MX, p[5]);
    }
    const float x0 = ((const float*)buf)[dl];
    const float xl = ((const float*)buf)[(size_t)(T0 - 1) * 8 + dl];
    const float Tf = (float)T0;
    const float mean = S1 / Tf;
    const float sxx  = S2 - S1 * S1 / Tf;
    const float stdv = sqrtf(fmaxf(sxx / (Tf - 1.f), 0.f));
    const float tbar = (Tf - 1.f) * 0.5f;
    const float Sic  = Tf * (Tf * Tf - 1.f) / 12.f;
    float trend = (St - tbar * S1) / sqrtf(sxx * Sic);
    if (isnan(trend)) trend = 0.f;
    const float na = Tf - 1.f;
    const float Sa = S1 - xl, Sb = S1 - x0;
    const float an  = C - Sa * Sb / na;
    const float sa2 = (S2 - xl * xl) - Sa * Sa / na;
    const float sb2 = (S2 - x0 * x0) - Sb * Sb / na;
    float ac = an / sqrtf(sa2 * sb2);
    if (isnan(ac)) ac = 0.f;
    perd[dl][0] = mean; perd[dl][1] = stdv; perd[dl][2] = MN;
    perd[dl][3] = MX;   perd[dl][4] = trend; perd[dl][5] = ac;
  }
  __syncthreads();   // scr reads done -> tw may be overwritten

  // ---- twiddles ----
  for (int k = tid; k < 1024; k += 512) {
    float sw, cw;
    sincosf(-(float)M_PI * (float)k * (1.0f / 1024.0f), &sw, &cw);
    tw[k] = make_float2(cw, sw);
  }
  __syncthreads();

  // ---- in-place DIF FFT, 2048-pt: 3 radix-8 passes + 1 radix-4 (unit) ----
  for (int stg = 0; stg < 9; stg += 3) {
    const int qsh = 8 - stg;            // log2(Q)
    const int Q = 1 << qsh;
    int pp = tid & 1;
    int gi = tid >> 1;                  // 0..255
    int j3 = gi & (Q - 1);
    int g  = gi >> qsh;
    int bs = (g << (qsh + 3)) + j3;
    float2 tA = tw[j3 << stg];
    float2 tB = tw[j3 << (stg + 1)];
    float2 tC = tw[j3 << (stg + 2)];
    float4 xx[8];
    #pragma unroll
    for (int mm = 0; mm < 8; ++mm) xx[mm] = buf[(bs + mm * Q) * 2 + pp];
    r8_fwd(xx, tA, tB, tC);
    #pragma unroll
    for (int mm = 0; mm < 8; ++mm) buf[(bs + mm * Q) * 2 + pp] = xx[mm];
    __syncthreads();
  }
  // tail radix-4 (stages 9,10; unit twiddles)
  #pragma unroll
  for (int it = 0; it < 2; ++it) {
    int sl = it * 512 + tid;
    int pp = sl & 1;
    int qi = sl >> 1;                   // 0..511
    int bs = qi << 2;
    float4 x0 = buf[bs*2+pp], x1 = buf[(bs+1)*2+pp];
    float4 x2 = buf[(bs+2)*2+pp], x3 = buf[(bs+3)*2+pp];
    float4 u0 = cadd(x0, x2);
    float4 t2 = csub(x0, x2);
    float4 u1 = cadd(x1, x3);
    float4 t3 = cmul_mi(csub(x1, x3));
    buf[bs*2+pp]     = cadd(u0, u1);
    buf[(bs+1)*2+pp] = csub(u0, u1);
    buf[(bs+2)*2+pp] = cadd(t2, t3);
    buf[(bs+3)*2+pp] = csub(t2, t3);
  }
  __syncthreads();
  // buf[p] = Z[rev11(p)]

  // ---- centroid: unpack real spectra per column, k = 0..1023 ----
  float4 num = {0,0,0,0}, den = {0,0,0,0};
  #pragma unroll
  for (int it = 0; it < 4; ++it) {
    int sl = it * 512 + tid;
    int pp = sl & 1;
    int k = sl >> 1;
    int p1 = __brev((unsigned)k) >> 21;
    int p2 = __brev((unsigned)((T0 - k) & (T0 - 1))) >> 21;
    float4 zk = buf[p1 * 2 + pp];
    float4 zm = buf[p2 * 2 + pp];
    float kf = (float)k;
    float arx = 0.5f*(zk.x+zm.x), ary = 0.5f*(zk.y-zm.y);
    float brx = 0.5f*(zk.y+zm.y), bry = 0.5f*(zm.x-zk.x);
    float pa = arx*arx + ary*ary, pb = brx*brx + bry*bry;
    num.x = fmaf(kf, pa, num.x); den.x += pa;
    num.y = fmaf(kf, pb, num.y); den.y += pb;
    arx = 0.5f*(zk.z+zm.z); ary = 0.5f*(zk.w-zm.w);
    brx = 0.5f*(zk.w+zm.w); bry = 0.5f*(zm.z-zk.z);
    pa = arx*arx + ary*ary; pb = brx*brx + bry*bry;
    num.z = fmaf(kf, pa, num.z); den.z += pa;
    num.w = fmaf(kf, pb, num.w); den.w += pb;
  }
  wredt_add<2>(num.x); wredt_add<2>(num.y); wredt_add<2>(num.z); wredt_add<2>(num.w);
  wredt_add<2>(den.x); wredt_add<2>(den.y); wredt_add<2>(den.z); wredt_add<2>(den.w);
  if (lane < 2) {
    float* p = scr + ((size_t)wv * 2 + f) * 8;
    p[0]=num.x; p[1]=num.y; p[2]=num.z; p[3]=num.w;
    p[4]=den.x; p[5]=den.y; p[6]=den.z; p[7]=den.w;
  }
  __syncthreads();
  if (tid < 8) {
    const int dl = tid;
    const int fq = dl >> 2, c = dl & 3;
    float N = 0.f, Dn = 0.f;
    for (int w = 0; w < 8; ++w) {
      const float* p = scr + ((size_t)w * 2 + fq) * 8;
      N += p[c]; Dn += p[4 + c];
    }
    float cent = N / Dn;
    if (isnan(cent)) cent = 0.f;
    perd[dl][6] = cent;
  }
  __syncthreads();
  if (tid < 7) {
    float s = 0.f;
    #pragma unroll
    for (int dl = 0; dl < 8; ++dl) s += perd[dl][tid];
    part[((size_t)b * 64 + eb) * 8 + tid] = s;
  }
}

// --------------- attn = sigmoid(relu(tda@w1+b1)@w2+b2); inj_l -----------------
__global__ __launch_bounds__(512) void k_weights(const float* __restrict__ part,
    const float* __restrict__ w1, const float* __restrict__ b1,
    const float* __restrict__ w2, const float* __restrict__ b2,
    const float* __restrict__ wi0, const float* __restrict__ bi0,
    const float* __restrict__ wi1, const float* __restrict__ bi1,
    const float* __restrict__ wi2, const float* __restrict__ bi2,
    float* __restrict__ attn, float* __restrict__ inj) {
  const int b = blockIdx.x;
  const int j = threadIdx.x;
  __shared__ float td[7];
  __shared__ float h[512];
  if (j < 7) {
    float s = 0.f;
    for (int w = 0; w < 64; ++w) s += part[((size_t)b * 64 + w) * 8 + j];
    td[j] = s * (1.0f / (float)D);
  }
  __syncthreads();
  float a = b1[j];
  #pragma unroll
  for (int f = 0; f < 7; ++f) a = fmaf(td[f], w1[f * D + j], a);
  h[j] = fmaxf(a, 0.0f);
  __syncthreads();
  float a2 = b2[j];
  for (int k = 0; k < D; ++k) a2 = fmaf(h[k], w2[k * D + j], a2);
  attn[(size_t)b * D + j] = 1.0f / (1.0f + expf(-a2));
  const float* wis[3] = {wi0, wi1, wi2};
  const float* bis[3] = {bi0, bi1, bi2};
  #pragma unroll
  for (int l = 0; l < 3; ++l) {
    float ai = bis[l][j];
    #pragma unroll
    for (int f = 0; f < 7; ++f) ai = fmaf(td[f], wis[l][f * D + j], ai);
    inj[(size_t)l * B * D + (size_t)b * D + j] = 0.3f * ai;
  }
}

// --------- FFT 2x spectral interp, batched 8 pairs/block, in-place ------------
// even: y[2j]   = S*z[j] + (-1)^j * Z[S/2]   (z kept in REGISTERS)
// odd:  y[2j+1] = IFFT_S(g), g[k] = sgn_k * Z[k] * e^{+i pi k/S}
//       g fused into the loads of the first inverse radix-8 pass.
// res = y/(4S); out = (high - res)*attn + inj. Evens+odds emitted together.
// Outputs nt-stored; all loads plain cached (R13: nt-loads demote L3 hits).
template<int S, int NT, bool COPY>
__global__ __launch_bounds__(NT) void k_interp(const float* __restrict__ low,
                                                const float* __restrict__ high,
                                                const float* __restrict__ attn,
                                                const float* __restrict__ inj,
                                                float* __restrict__ out,
                                                float* __restrict__ copy_out) {
  constexpr int LOG2S = (S == 1024) ? 10 : (S == 512) ? 9 : 8;
  constexpr int WAVES = NT / 64;
  constexpr int RPT   = S / (NT / 4);          // rows per thread
  constexpr int R8IT  = S / 2;                 // items per radix-8 pass
  __shared__ float4 buf[S * 4];
  __shared__ float2 tw[S];
  __shared__ float4 scrA[WAVES][4];
  __shared__ float4 Zh4[4];
  const int tid  = threadIdx.x;
  // pairing swizzle: partner blocks (eb pair sharing 128B lines) differ by 8
  const int L = blockIdx.x + 32 * blockIdx.y;  // grid (32, 32) flat 0..1023
  const int m = (L >> 3) & 1;
  const int q = (L & 7) | ((L >> 4) << 3);     // 0..511
  const int eb = (q & 15) * 2 + m;             // 0..31
  const int b  = q >> 4;                       // 0..31
  const int f    = tid & 3;
  const int rIdx = tid >> 2;
  const int lane = tid & 63;
  const int wv   = tid >> 6;
  const int d0   = eb * 16;

  const float* lowb  = low  + (size_t)b * S * D + d0 + 4 * f;
  const float* highb = high + (size_t)b * (2 * S) * D + d0 + 4 * f;
  float*       outb  = out  + (size_t)b * (2 * S) * D + d0 + 4 * f;
  float*       cpb   = COPY ? copy_out + (size_t)b * S * D + d0 + 4 * f : nullptr;

  // ---- load (full-line rows) + z kept in regs + alternating-sum partials ----
  float4 zreg[RPT];
  float4 acc = {0,0,0,0};
  #pragma unroll
  for (int u = 0; u < RPT; ++u) {
    int t = rIdx + (NT / 4) * u;
    float4 v = *(const float4*)&lowb[(size_t)t * D];
    zreg[u] = v;
    buf[t * 4 + f] = v;
    if (COPY) nt_store4(&cpb[(size_t)t * D], v);
    acc.x += v.x; acc.y += v.y; acc.z += v.z; acc.w += v.w;
  }
  if (rIdx & 1) { acc.x = -acc.x; acc.y = -acc.y; acc.z = -acc.z; acc.w = -acc.w; }
  for (int k = tid; k < S; k += NT) {
    float sw, cw;
    sincosf(-(float)M_PI * (float)k * (1.0f / (float)S), &sw, &cw);
    tw[k] = make_float2(cw, sw);
  }
  wred_add(acc.x); wred_add(acc.y); wred_add(acc.z); wred_add(acc.w);
  if (lane < 4) scrA[wv][f] = acc;             // f == lane
  __syncthreads();
  if (tid < 4) {
    float4 s = scrA[0][tid];
    for (int w = 1; w < WAVES; ++w) {
      float4 qv = scrA[w][tid];
      s.x += qv.x; s.y += qv.y; s.z += qv.z; s.w += qv.w;
    }
    Zh4[tid] = s;
  }
  __syncthreads();

  const float inv4S = 1.0f / (4.0f * (float)S);
  const float4 at4 = *(const float4*)&attn[(size_t)b * D + d0 + 4 * f];
  const float4 in4 = *(const float4*)&inj [(size_t)b * D + d0 + 4 * f];
  float4 Zs = Zh4[f];
  Zs.x *= inv4S; Zs.y *= inv4S; Zs.z *= inv4S; Zs.w *= inv4S;

  // ---- forward DIF (natural -> bitrev), radix-8 passes ----
  for (int stg = 0; stg + 2 < LOG2S; stg += 3) {
    const int qsh = LOG2S - 3 - stg;
    const int Q = 1 << qsh;
    #pragma unroll
    for (int it = 0; it < (R8IT + NT - 1) / NT; ++it) {
      int sl = it * NT + tid;
      if (sl < R8IT) {
        int pp = sl & 3;
        int gi = sl >> 2;
        int j3 = gi & (Q - 1);
        int g  = gi >> qsh;
        int bs = (g << (qsh + 3)) + j3;
        float2 tA = tw[j3 << (stg + 1)];
        float2 tB = tw[j3 << (stg + 2)];
        float2 tC = tw[j3 << (stg + 3)];
        float4 xx[8];
        #pragma unroll
        for (int mm = 0; mm < 8; ++mm) xx[mm] = buf[(bs + mm * Q) * 4 + pp];
        r8_fwd(xx, tA, tB, tC);
        #pragma unroll
        for (int mm = 0; mm < 8; ++mm) buf[(bs + mm * Q) * 4 + pp] = xx[mm];
      }
      __syncthreads();
    }
  }
  if (LOG2S % 3 == 1) {                  // tail radix-2 (unit twiddles)
    #pragma unroll
    for (int it = 0; it < (2 * S) / NT; ++it) {
      int sl = it * NT + tid;
      int pp = sl & 3;
      int bi = sl >> 2;
      int i = bi * 2;
      float4 a = buf[i * 4 + pp];
      float4 c4 = buf[(i + 1) * 4 + pp];
      buf[i * 4 + pp]       = cadd(a, c4);
      buf[(i + 1) * 4 + pp] = csub(a, c4);
    }
    __syncthreads();
  }
  if (LOG2S % 3 == 2) {                  // tail radix-4 (unit twiddles)
    #pragma unroll
    for (int it = 0; it < S / NT; ++it) {
      int sl = it * NT + tid;
      int pp = sl & 3;
      int qi = sl >> 2;
      int bs = qi << 2;
      float4 x0 = buf[bs*4+pp], x1 = buf[(bs+1)*4+pp];
      float4 x2 = buf[(bs+2)*4+pp], x3 = buf[(bs+3)*4+pp];
      float4 u0 = cadd(x0, x2);
      float4 t2 = csub(x0, x2);
      float4 u1 = cadd(x1, x3);
      float4 t3 = cmul_mi(csub(x1, x3));
      buf[bs*4+pp]     = cadd(u0, u1);
      buf[(bs+1)*4+pp] = csub(u0, u1);
      buf[(bs+2)*4+pp] = cadd(t2, t3);
      buf[(bs+3)*4+pp] = csub(t2, t3);
    }
    __syncthreads();
  }
  // buf[p] = Z[rev(p)]

  // ---- inverse DIT (bitrev -> natural), radix-8 passes; g fused in pass 0 ----
  for (int stg = 0; stg + 2 < LOG2S; stg += 3) {
    const int h = 1 << stg;
    #pragma unroll
    for (int it = 0; it < (R8IT + NT - 1) / NT; ++it) {
      int sl = it * NT + tid;
      if (sl < R8IT) {
        int pp = sl & 3;
        int gi = sl >> 2;
        int j  = gi & (h - 1);
        int G  = gi >> stg;
        int bs = (G << (stg + 3)) + j;
        float2 wA = tw[j << (LOG2S - stg)];
        float2 wB = tw[j << (LOG2S - stg - 1)];
        float2 wC = tw[j << (LOG2S - stg - 2)];
        float4 xx[8];
        if (stg == 0) {
          #pragma unroll
          for (int mm = 0; mm < 8; ++mm) {
            int p = bs + mm;
            int k = __brev((unsigned)p) >> (32 - LOG2S);
            float2 w = tw[k];
            float sgn = (k < S / 2) ? 1.f : (k == S / 2) ? 0.f : -1.f;
            float4 v = cmulc(buf[p * 4 + pp], w);
            v.x *= sgn; v.y *= sgn; v.z *= sgn; v.w *= sgn;
            xx[mm] = v;
          }
        } else {
          #pragma unroll
          for (int mm = 0; mm < 8; ++mm) xx[mm] = buf[(bs + mm * h) * 4 + pp];
        }
        r8_inv(xx, wA, wB, wC);
        #pragma unroll
        for (int mm = 0; mm < 8; ++mm) buf[(bs + mm * h) * 4 + pp] = xx[mm];
      }
      __syncthreads();
    }
  }
  if (LOG2S % 3 == 1) {                  // tail radix-2 at stg = LOG2S-1
    const int stg = LOG2S - 1;
    const int h = 1 << stg;
    #pragma unroll
    for (int it = 0; it < (2 * S) / NT; ++it) {
      int sl = it * NT + tid;
      int pp = sl & 3;
      int bi = sl >> 2;
      int j = bi & (h - 1);
      int g = bi >> stg;
      int i = (g << (stg + 1)) + j;
      float2 w = tw[j << (LOG2S - stg)];
      float4 a = buf[i * 4 + pp];
      float4 v = buf[(i + h) * 4 + pp];
      float4 t = cmulc(v, w);
      buf[i * 4 + pp]       = cadd(a, t);
      buf[(i + h) * 4 + pp] = csub(a, t);
    }
    __syncthreads();
  }
  if (LOG2S % 3 == 2) {                  // tail radix-4 at stg = LOG2S-2
    const int stg = LOG2S - 2;
    const int h = 1 << stg;
    #pragma unroll
    for (int it = 0; it < S / NT; ++it) {
      int sl = it * NT + tid;
      int pp = sl & 3;
      int qi = sl >> 2;
      int j = qi & (h - 1);
      int g = qi >> stg;
      int bs = (g << (stg + 2)) + j;
      float2 wA = tw[j << (LOG2S - stg)];
      float2 wB = tw[j << (LOG2S - stg - 1)];
      float4 x0 = buf[bs * 4 + pp];
      float4 x1 = buf[(bs + h) * 4 + pp];
      float4 x2 = buf[(bs + 2 * h) * 4 + pp];
      float4 x3 = buf[(bs + 3 * h) * 4 + pp];
      float4 t1 = cmulc(x1, wA);
      float4 u0 = cadd(x0, t1), u1 = csub(x0, t1);
      float4 t3 = cmulc(x3, wA);
      float4 u2 = cadd(x2, t3), u3 = csub(x2, t3);
      float4 s2c = cmulc(u2, wB);
      float4 s3c = cmul_pi(cmulc(u3, wB));
      buf[bs * 4 + pp]           = cadd(u0, s2c);
      buf[(bs + h) * 4 + pp]     = cadd(u1, s3c);
      buf[(bs + 2 * h) * 4 + pp] = csub(u0, s2c);
      buf[(bs + 3 * h) * 4 + pp] = csub(u1, s3c);
    }
    __syncthreads();
  }

  // ---- even + odd outputs together (adjacent row pairs), non-temporal ----
  #pragma unroll
  for (int u = 0; u < RPT; ++u) {
    int j = rIdx + (NT / 4) * u;
    float4 z = zreg[u];
    float sg = (j & 1) ? -1.f : 1.f;
    float4 res_e;
    res_e.x = fmaf(0.25f, z.x, sg * Zs.x);
    res_e.y = fmaf(0.25f, z.y, sg * Zs.y);
    res_e.z = fmaf(0.25f, z.z, sg * Zs.z);
    res_e.w = fmaf(0.25f, z.w, sg * Zs.w);
    float4 y = buf[j * 4 + f];
    float4 h0 = *(const float4*)&highb[(size_t)(2 * j) * D];
    float4 h1 = *(const float4*)&highb[(size_t)(2 * j + 1) * D];
    float4 o0, o1;
    o0.x = fmaf(h0.x - res_e.x, at4.x, in4.x);
    o0.y = fmaf(h0.y - res_e.y, at4.y, in4.y);
    o0.z = fmaf(h0.z - res_e.z, at4.z, in4.z);
    o0.w = fmaf(h0.w - res_e.w, at4.w, in4.w);
    o1.x = fmaf(h1.x - y.x * inv4S, at4.x, in4.x);
    o1.y = fmaf(h1.y - y.y * inv4S, at4.y, in4.y);
    o1.z = fmaf(h1.z - y.z * inv4S, at4.z, in4.z);
    o1.w = fmaf(h1.w - y.w * inv4S, at4.w, in4.w);
    nt_store4(&outb[(size_t)(2 * j) * D], o0);
    nt_store4(&outb[(size_t)(2 * j + 1) * D], o1);
  }
}

extern "C" void kernel_launch(void* const* d_in, const int* in_sizes, int n_in,
                              void* d_out, int out_size, void* d_ws, size_t ws_size,
                              hipStream_t stream) {
  const float* level0 = (const float*)d_in[0];
  const float* level1 = (const float*)d_in[1];
  const float* level2 = (const float*)d_in[2];
  const float* level3 = (const float*)d_in[3];
  const float* w1  = (const float*)d_in[4];
  const float* b1  = (const float*)d_in[5];
  const float* w2  = (const float*)d_in[6];
  const float* b2  = (const float*)d_in[7];
  const float* wi0 = (const float*)d_in[8];
  const float* bi0 = (const float*)d_in[9];
  const float* wi1 = (const float*)d_in[10];
  const float* bi1 = (const float*)d_in[11];
  const float* wi2 = (const float*)d_in[12];
  const float* bi2 = (const float*)d_in[13];

  float* ws   = (float*)d_ws;
  float* part = ws + OFF_PART;
  float* attn = ws + OFF_ATTN;
  float* inj  = ws + OFF_INJ;

  float* out0 = (float*)d_out;                       // (32,2048,512)
  float* out1 = out0 + (size_t)B * 2048 * D;         // (32,1024,512)
  float* out2 = out1 + (size_t)B * 1024 * D;         // (32, 512,512)
  float* out3 = out2 + (size_t)B * 512 * D;          // (32, 256,512)

  k_tda<<<dim3(64, B), 512, 0, stream>>>(level0, part);
  k_weights<<<B, 512, 0, stream>>>(part, w1, b1, w2, b2, wi0, bi0, wi1, bi1, wi2, bi2,
                                   attn, inj);

  k_interp<1024, 512, false><<<dim3(32, B), 512, 0, stream>>>(
      level1, level0, attn, inj + 0ull * B * D, out0, nullptr);
  k_interp<512, 512, false><<<dim3(32, B), 512, 0, stream>>>(
      level2, level1, attn, inj + 1ull * B * D, out1, nullptr);
  k_interp<256, 256, true><<<dim3(32, B), 256, 0, stream>>>(
      level3, level2, attn, inj + 2ull * B * D, out2, out3);
}